// Round 1
// baseline (597.696 us; speedup 1.0000x reference)
//
#include <hip/hip_runtime.h>
#include <math.h>

#define T_DIM 2048
#define C_DIM 1024
#define H_NUM 16
#define HD_DIM 64
#define K_LCP 8
#define NEG_VAL -1.0e9f

// ---------------- GEMM fp32: C[M,N] = A[M,K] * B[K,N], row-major ----------------
#define BM 64
#define BN 64
#define BKT 16

__global__ __launch_bounds__(256) void gemm_f32(const float* __restrict__ A,
                                                const float* __restrict__ B,
                                                float* __restrict__ C,
                                                int M, int N, int Kd) {
  __shared__ float As[BKT][BM + 4];  // As[k][m], padded stride for write conflicts
  __shared__ float Bs[BKT][BN];     // Bs[k][n]
  const int tid = threadIdx.x;
  const int bm = blockIdx.y * BM;
  const int bn = blockIdx.x * BN;
  const int tm = (tid >> 4) * 4;   // 0..60
  const int tn = (tid & 15) * 4;   // 0..60
  const int am = tid >> 2;         // 0..63
  const int ak = (tid & 3) * 4;    // 0,4,8,12
  const int bk = tid >> 4;         // 0..15
  const int bn4 = (tid & 15) * 4;  // 0..60

  float acc[4][4] = {};
  for (int k0 = 0; k0 < Kd; k0 += BKT) {
    float4 a4 = *(const float4*)(A + (size_t)(bm + am) * Kd + k0 + ak);
    float4 b4 = *(const float4*)(B + (size_t)(k0 + bk) * N + bn + bn4);
    __syncthreads();  // protect previous iteration's LDS reads
    As[ak + 0][am] = a4.x;
    As[ak + 1][am] = a4.y;
    As[ak + 2][am] = a4.z;
    As[ak + 3][am] = a4.w;
    *(float4*)&Bs[bk][bn4] = b4;
    __syncthreads();
#pragma unroll
    for (int kk = 0; kk < BKT; ++kk) {
      float ar[4], br[4];
      *(float4*)ar = *(const float4*)&As[kk][tm];
      *(float4*)br = *(const float4*)&Bs[kk][tn];
#pragma unroll
      for (int i = 0; i < 4; ++i)
#pragma unroll
        for (int j = 0; j < 4; ++j) acc[i][j] = fmaf(ar[i], br[j], acc[i][j]);
    }
  }
#pragma unroll
  for (int i = 0; i < 4; ++i) {
    float4 o = make_float4(acc[i][0], acc[i][1], acc[i][2], acc[i][3]);
    *(float4*)(C + (size_t)(bm + tm + i) * N + bn + tn) = o;
  }
}

// ---------------- qd = x@Wdq, kd = x@Wdk : one block (128 thr) per row t --------
__global__ __launch_bounds__(128) void qdkd_kernel(const float* __restrict__ x,
                                                   const float* __restrict__ Wdq,
                                                   const float* __restrict__ Wdk,
                                                   float* __restrict__ qd,
                                                   float* __restrict__ kd) {
  __shared__ float xs[C_DIM];
  const int t = blockIdx.x;
  for (int i4 = threadIdx.x; i4 < C_DIM / 4; i4 += 128)
    ((float4*)xs)[i4] = ((const float4*)(x + (size_t)t * C_DIM))[i4];
  __syncthreads();

  const int wave = threadIdx.x >> 6;  // 0 -> qd, 1 -> kd
  const int lane = threadIdx.x & 63;
  const int j = lane >> 3;  // 0..7 output col
  const int s = lane & 7;   // strip
  const float* W = wave ? Wdk : Wdq;
  float* outp = wave ? kd : qd;
  float acc = 0.f;
  for (int c = s; c < C_DIM; c += 8) acc = fmaf(xs[c], W[(size_t)c * K_LCP + j], acc);
  acc += __shfl_xor(acc, 1);
  acc += __shfl_xor(acc, 2);
  acc += __shfl_xor(acc, 4);
  if (s == 0) outp[(size_t)t * K_LCP + j] = acc;
}

// ---------------- RoPE + RMS-norm, in place on q and k --------------------------
__global__ __launch_bounds__(256) void rope_rms(float* __restrict__ qp,
                                                float* __restrict__ kp,
                                                const float* __restrict__ cosT,
                                                const float* __restrict__ sinT) {
  const int row = blockIdx.x * 8 + (threadIdx.x >> 5);  // row in [0, T*H)
  const int i = threadIdx.x & 31;
  float* base = blockIdx.y ? kp : qp;
  const int t = row >> 4;  // H = 16
  float* p = base + (size_t)row * HD_DIM;
  float x1 = p[i], x2 = p[i + 32];
  float c = cosT[(size_t)t * 32 + i], s = sinT[(size_t)t * 32 + i];
  float o1 = x1 * c - x2 * s;
  float o2 = x1 * s + x2 * c;
  float sq = o1 * o1 + o2 * o2;
#pragma unroll
  for (int m = 1; m < 32; m <<= 1) sq += __shfl_xor(sq, m);
  float r = 1.0f / sqrtf(sq * (1.0f / 64.0f) + 1e-6f);
  p[i] = o1 * r;
  p[i + 32] = o2 * r;
}

// ---------------- Flash attention with LCP mask + masked-tile skip --------------
#define QT 16
#define KT 64

__global__ __launch_bounds__(256) void attn_kernel(const float* __restrict__ q,
                                                   const float* __restrict__ k,
                                                   const float* __restrict__ v,
                                                   const float* __restrict__ qd,
                                                   const float* __restrict__ kd,
                                                   float* __restrict__ y) {
  const int h = blockIdx.y;
  const int q0 = blockIdx.x * QT;
  const int tid = threadIdx.x;

  __shared__ float qs[QT][HD_DIM];
  __shared__ float qds[QT][K_LCP];
  __shared__ float ks[KT][HD_DIM];
  __shared__ float vs[KT][HD_DIM];
  __shared__ float kds[KT][K_LCP];
  __shared__ float sc[QT][KT + 4];

  // stage q tile (pre-scaled by 1/sqrt(HD)) and qd tile
  {
    int r = tid >> 4;
    int c4 = (tid & 15) * 4;
    float4 t4 = *(const float4*)(q + (size_t)(q0 + r) * C_DIM + h * HD_DIM + c4);
    qs[r][c4 + 0] = t4.x * 0.125f;
    qs[r][c4 + 1] = t4.y * 0.125f;
    qs[r][c4 + 2] = t4.z * 0.125f;
    qs[r][c4 + 3] = t4.w * 0.125f;
    if (tid < QT * K_LCP)
      qds[tid >> 3][tid & 7] = qd[(size_t)(q0 + (tid >> 3)) * K_LCP + (tid & 7)];
  }

  const int q_l = tid >> 4;   // 0..15 query row
  const int sub = tid & 15;   // owns dims sub*4 .. sub*4+3
  float m = -INFINITY;
  float l = 0.f;
  float acc[4] = {0.f, 0.f, 0.f, 0.f};

  for (int k0 = 0; k0 < T_DIM; k0 += KT) {
    __syncthreads();  // protect vs/sc reads of previous tile
    // stage V tile + kd tile (always needed)
#pragma unroll
    for (int it = 0; it < 4; ++it) {
      int i = tid + it * 256;  // float4 index 0..1023
      int row = i >> 4, c4 = (i & 15) * 4;
      *(float4*)&vs[row][c4] =
          *(const float4*)(v + (size_t)(k0 + row) * C_DIM + h * HD_DIM + c4);
    }
#pragma unroll
    for (int it = 0; it < 2; ++it) {
      int i = tid + it * 256;  // 0..511
      kds[i >> 3][i & 7] = kd[(size_t)(k0 + (i >> 3)) * K_LCP + (i & 7)];
    }
    __syncthreads();

    // mask for my 4 keys
    const int kb = sub * 4;
    bool msk[4];
    int any_local = 0;
#pragma unroll
    for (int j = 0; j < 4; ++j) {
      int kg = k0 + kb + j;
      int lcp = 0;
#pragma unroll
      for (int jj = 0; jj < K_LCP; ++jj) {
        if (qds[q_l][jj] == kds[kb + j][jj]) lcp++;
        else break;
      }
      msk[j] = (lcp >= K_LCP - 1) && (kg <= q0 + q_l);
      any_local |= (int)msk[j];
    }
    const int anyU = __syncthreads_or(any_local);

    if (!anyU) {
      // exact fast path: all scores in tile are NEG.
      // if m > NEG: exp(NEG - m) underflows to exactly 0 -> tile contributes nothing.
      if (m <= NEG_VAL) {
        m = NEG_VAL;
        l += (float)KT;
#pragma unroll 8
        for (int kk = 0; kk < KT; ++kk) {
          const float4 v4 = *(const float4*)&vs[kk][sub * 4];
          acc[0] += v4.x; acc[1] += v4.y; acc[2] += v4.z; acc[3] += v4.w;
        }
      }
      continue;
    }

    // full path: stage K tile
#pragma unroll
    for (int it = 0; it < 4; ++it) {
      int i = tid + it * 256;
      int row = i >> 4, c4 = (i & 15) * 4;
      *(float4*)&ks[row][c4] =
          *(const float4*)(k + (size_t)(k0 + row) * C_DIM + h * HD_DIM + c4);
    }
    __syncthreads();

    float s[4] = {0.f, 0.f, 0.f, 0.f};
#pragma unroll
    for (int d4 = 0; d4 < 16; ++d4) {
      float4 q4 = *(const float4*)&qs[q_l][d4 * 4];
#pragma unroll
      for (int j = 0; j < 4; ++j) {
        float4 k4 = *(const float4*)&ks[kb + j][d4 * 4];
        s[j] = fmaf(q4.x, k4.x, s[j]);
        s[j] = fmaf(q4.y, k4.y, s[j]);
        s[j] = fmaf(q4.z, k4.z, s[j]);
        s[j] = fmaf(q4.w, k4.w, s[j]);
      }
    }
    float tmax = NEG_VAL;
#pragma unroll
    for (int j = 0; j < 4; ++j) {
      s[j] = msk[j] ? s[j] : NEG_VAL;
      tmax = fmaxf(tmax, s[j]);
    }
#pragma unroll
    for (int off = 1; off < 16; off <<= 1) tmax = fmaxf(tmax, __shfl_xor(tmax, off));
    float m_new = fmaxf(m, tmax);
    float alpha = expf(m - m_new);
    float lsum = 0.f;
#pragma unroll
    for (int j = 0; j < 4; ++j) {
      float p = expf(s[j] - m_new);
      sc[q_l][kb + j] = p;
      lsum += p;
    }
#pragma unroll
    for (int off = 1; off < 16; off <<= 1) lsum += __shfl_xor(lsum, off);
    l = l * alpha + lsum;
    m = m_new;
    acc[0] *= alpha; acc[1] *= alpha; acc[2] *= alpha; acc[3] *= alpha;
    __syncthreads();  // p values visible to all row threads
#pragma unroll 8
    for (int kk = 0; kk < KT; ++kk) {
      float w = sc[q_l][kk];
      const float4 v4 = *(const float4*)&vs[kk][sub * 4];
      acc[0] = fmaf(w, v4.x, acc[0]);
      acc[1] = fmaf(w, v4.y, acc[1]);
      acc[2] = fmaf(w, v4.z, acc[2]);
      acc[3] = fmaf(w, v4.w, acc[3]);
    }
  }

  const float inv_l = 1.0f / l;
  float4 o = make_float4(acc[0] * inv_l, acc[1] * inv_l, acc[2] * inv_l, acc[3] * inv_l);
  *(float4*)(y + (size_t)(q0 + q_l) * C_DIM + h * HD_DIM + sub * 4) = o;
}

extern "C" void kernel_launch(void* const* d_in, const int* in_sizes, int n_in,
                              void* d_out, int out_size, void* d_ws, size_t ws_size,
                              hipStream_t stream) {
  const float* x = (const float*)d_in[0];
  const float* cosT = (const float*)d_in[1];
  const float* sinT = (const float*)d_in[2];
  const float* Wq = (const float*)d_in[3];
  const float* Wk = (const float*)d_in[4];
  const float* Wv = (const float*)d_in[5];
  const float* Wproj = (const float*)d_in[6];
  const float* Wdq = (const float*)d_in[7];
  const float* Wdk = (const float*)d_in[8];
  float* out = (float*)d_out;

  float* ws = (float*)d_ws;
  float* q = ws;
  float* k = q + (size_t)T_DIM * C_DIM;
  float* v = k + (size_t)T_DIM * C_DIM;
  float* y = v + (size_t)T_DIM * C_DIM;
  float* qd = y + (size_t)T_DIM * C_DIM;
  float* kd = qd + (size_t)T_DIM * K_LCP;

  dim3 gg(C_DIM / BN, T_DIM / BM);
  gemm_f32<<<gg, 256, 0, stream>>>(x, Wq, q, T_DIM, C_DIM, C_DIM);
  gemm_f32<<<gg, 256, 0, stream>>>(x, Wk, k, T_DIM, C_DIM, C_DIM);
  gemm_f32<<<gg, 256, 0, stream>>>(x, Wv, v, T_DIM, C_DIM, C_DIM);
  qdkd_kernel<<<T_DIM, 128, 0, stream>>>(x, Wdq, Wdk, qd, kd);
  rope_rms<<<dim3(T_DIM * H_NUM / 8, 2), 256, 0, stream>>>(q, k, cosT, sinT);
  attn_kernel<<<dim3(T_DIM / QT, H_NUM), 256, 0, stream>>>(q, k, v, qd, kd, y);
  gemm_f32<<<gg, 256, 0, stream>>>(y, Wproj, out, T_DIM, C_DIM, C_DIM);
}

// Round 2
// 241.145 us; speedup vs baseline: 2.4786x; 2.4786x over previous
//
#include <hip/hip_runtime.h>
#include <math.h>

#define T_DIM 2048
#define C_DIM 1024
#define H_NUM 16
#define HD_DIM 64
#define K_LCP 8
#define NEG_VAL -1.0e9f

typedef __bf16 bf16;
typedef __bf16 bf16x4 __attribute__((ext_vector_type(4)));
typedef __bf16 bf16x8 __attribute__((ext_vector_type(8)));
typedef float f32x4 __attribute__((ext_vector_type(4)));

// ---------------- convert x fp32 -> bf16 ----------------
__global__ __launch_bounds__(256) void convert_x(const float* __restrict__ x,
                                                 bf16* __restrict__ xb) {
  int i = blockIdx.x * 256 + threadIdx.x;  // float4 index, n/4 total
  float4 f = ((const float4*)x)[i];
  bf16x4 o = {(bf16)f.x, (bf16)f.y, (bf16)f.z, (bf16)f.w};
  ((bf16x4*)xb)[i] = o;
}

// ---------------- transpose + convert weights: W[K][N] fp32 -> Wt[N][K] bf16 ----
__global__ __launch_bounds__(256) void transpose_w(const float* __restrict__ W0,
                                                   const float* __restrict__ W1,
                                                   const float* __restrict__ W2,
                                                   const float* __restrict__ W3,
                                                   bf16* __restrict__ O0,
                                                   bf16* __restrict__ O1,
                                                   bf16* __restrict__ O2,
                                                   bf16* __restrict__ O3) {
  const float* W = (blockIdx.z == 0) ? W0 : (blockIdx.z == 1) ? W1
                   : (blockIdx.z == 2) ? W2 : W3;
  bf16* O = (blockIdx.z == 0) ? O0 : (blockIdx.z == 1) ? O1
            : (blockIdx.z == 2) ? O2 : O3;
  __shared__ bf16 tile[64][65];
  const int bk = blockIdx.y * 64;  // rows of W (k)
  const int bn = blockIdx.x * 64;  // cols of W (n)
  const int r = threadIdx.x >> 2;
  const int c0 = (threadIdx.x & 3) * 16;
  const float* src = W + (size_t)(bk + r) * C_DIM + bn + c0;
#pragma unroll
  for (int t = 0; t < 16; t += 4) {
    float4 f = *(const float4*)(src + t);
    tile[r][c0 + t + 0] = (bf16)f.x;
    tile[r][c0 + t + 1] = (bf16)f.y;
    tile[r][c0 + t + 2] = (bf16)f.z;
    tile[r][c0 + t + 3] = (bf16)f.w;
  }
  __syncthreads();
  bf16* dst = O + (size_t)(bn + r) * C_DIM + bk + c0;
#pragma unroll
  for (int t = 0; t < 16; ++t) dst[t] = tile[c0 + t][r];
}

// ---------------- bf16 MFMA GEMM: C[M][N] = A[M][K] * Bt[N][K]^T ----------------
#define TM 128
#define TN 128
#define GBK 32
#define LDA 48  // LDS row stride (elements), 96B: 16B-aligned, spreads banks

__global__ __launch_bounds__(256) void gemm_bf16(
    const bf16* __restrict__ A, const bf16* __restrict__ Bt0,
    const bf16* __restrict__ Bt1, const bf16* __restrict__ Bt2, void* C0,
    void* C1, void* C2, int M, int N, int Kd, int bf16_out) {
  const bf16* Bt = (blockIdx.z == 0) ? Bt0 : (blockIdx.z == 1) ? Bt1 : Bt2;
  __shared__ __align__(16) bf16 As[TM * LDA];
  __shared__ __align__(16) bf16 Bs[TN * LDA];
  const int tid = threadIdx.x;
  const int bm = blockIdx.y * TM;
  const int bn = blockIdx.x * TN;
  const int row2 = tid >> 1;       // 0..127 staging row
  const int kh = (tid & 1) * 16;   // staging k-half
  const int wave = tid >> 6;
  const int lane = tid & 63;
  const int wr = (wave >> 1) * 64;  // wave row offset in tile
  const int wc = (wave & 1) * 64;   // wave col offset
  const int fm = lane & 15;         // fragment m/n index
  const int fk = (lane >> 4) * 8;   // fragment k offset

  f32x4 acc[4][4] = {};
  const bf16* Aptr = A + (size_t)(bm + row2) * Kd + kh;
  const bf16* Bptr = Bt + (size_t)(bn + row2) * Kd + kh;

  for (int k0 = 0; k0 < Kd; k0 += GBK) {
    bf16x8 a0 = *(const bf16x8*)(Aptr + k0);
    bf16x8 a1 = *(const bf16x8*)(Aptr + k0 + 8);
    bf16x8 b0 = *(const bf16x8*)(Bptr + k0);
    bf16x8 b1 = *(const bf16x8*)(Bptr + k0 + 8);
    __syncthreads();
    *(bf16x8*)(As + row2 * LDA + kh) = a0;
    *(bf16x8*)(As + row2 * LDA + kh + 8) = a1;
    *(bf16x8*)(Bs + row2 * LDA + kh) = b0;
    *(bf16x8*)(Bs + row2 * LDA + kh + 8) = b1;
    __syncthreads();
    bf16x8 af[4], bfr[4];
#pragma unroll
    for (int i = 0; i < 4; ++i) {
      af[i] = *(const bf16x8*)(As + (size_t)(wr + i * 16 + fm) * LDA + fk);
      bfr[i] = *(const bf16x8*)(Bs + (size_t)(wc + i * 16 + fm) * LDA + fk);
    }
#pragma unroll
    for (int i = 0; i < 4; ++i)
#pragma unroll
      for (int j = 0; j < 4; ++j)
        acc[i][j] = __builtin_amdgcn_mfma_f32_16x16x32_bf16(af[i], bfr[j],
                                                            acc[i][j], 0, 0, 0);
  }
  const int cq = (lane >> 4) * 4;
  if (bf16_out) {
    bf16* C = (bf16*)((blockIdx.z == 0) ? C0 : (blockIdx.z == 1) ? C1 : C2);
#pragma unroll
    for (int i = 0; i < 4; ++i)
#pragma unroll
      for (int r = 0; r < 4; ++r) {
        size_t base = (size_t)(bm + wr + i * 16 + cq + r) * N + bn + wc + fm;
#pragma unroll
        for (int j = 0; j < 4; ++j) C[base + j * 16] = (bf16)acc[i][j][r];
      }
  } else {
    float* C = (float*)((blockIdx.z == 0) ? C0 : (blockIdx.z == 1) ? C1 : C2);
#pragma unroll
    for (int i = 0; i < 4; ++i)
#pragma unroll
      for (int r = 0; r < 4; ++r) {
        size_t base = (size_t)(bm + wr + i * 16 + cq + r) * N + bn + wc + fm;
#pragma unroll
        for (int j = 0; j < 4; ++j) C[base + j * 16] = acc[i][j][r];
      }
  }
}

// ---------------- qd = x@Wdq, kd = x@Wdk (fp32, exact-match semantics) ----------
__global__ __launch_bounds__(128) void qdkd_kernel(const float* __restrict__ x,
                                                   const float* __restrict__ Wdq,
                                                   const float* __restrict__ Wdk,
                                                   float* __restrict__ qd,
                                                   float* __restrict__ kd) {
  __shared__ float xs[C_DIM];
  const int t = blockIdx.x;
  for (int i4 = threadIdx.x; i4 < C_DIM / 4; i4 += 128)
    ((float4*)xs)[i4] = ((const float4*)(x + (size_t)t * C_DIM))[i4];
  __syncthreads();
  const int wave = threadIdx.x >> 6;
  const int lane = threadIdx.x & 63;
  const int j = lane >> 3;
  const int s = lane & 7;
  const float* W = wave ? Wdk : Wdq;
  float* outp = wave ? kd : qd;
  float acc = 0.f;
  for (int c = s; c < C_DIM; c += 8) acc = fmaf(xs[c], W[(size_t)c * K_LCP + j], acc);
  acc += __shfl_xor(acc, 1);
  acc += __shfl_xor(acc, 2);
  acc += __shfl_xor(acc, 4);
  if (s == 0) outp[(size_t)t * K_LCP + j] = acc;
}

// ---------------- RoPE + RMS-norm on bf16 q,k in place --------------------------
__global__ __launch_bounds__(256) void rope_rms(bf16* __restrict__ qp,
                                                bf16* __restrict__ kp,
                                                const float* __restrict__ cosT,
                                                const float* __restrict__ sinT) {
  const int row = blockIdx.x * 8 + (threadIdx.x >> 5);  // [0, T*H)
  const int i = threadIdx.x & 31;
  bf16* base = blockIdx.y ? kp : qp;
  const int t = row >> 4;
  bf16* p = base + (size_t)row * HD_DIM;
  float x1 = (float)p[i], x2 = (float)p[i + 32];
  float c = cosT[(size_t)t * 32 + i], s = sinT[(size_t)t * 32 + i];
  float o1 = x1 * c - x2 * s;
  float o2 = x1 * s + x2 * c;
  float sq = o1 * o1 + o2 * o2;
#pragma unroll
  for (int m = 1; m < 32; m <<= 1) sq += __shfl_xor(sq, m);
  float r = 1.0f / sqrtf(sq * (1.0f / 64.0f) + 1e-6f);
  p[i] = (bf16)(o1 * r);
  p[i + 32] = (bf16)(o2 * r);
}

// ---------------- tilemask[qb][kt]: any unmasked (causal && lcp>=K-1) pair ------
__global__ __launch_bounds__(256) void tilemask_kernel(const float* __restrict__ qd,
                                                       const float* __restrict__ kd,
                                                       int* __restrict__ tilemask) {
  const int qb = blockIdx.x;
  __shared__ float qds[16][K_LCP];
  __shared__ int tm[32];
  const int tid = threadIdx.x;
  if (tid < 32) tm[tid] = 0;
  if (tid < 16 * K_LCP)
    qds[tid >> 3][tid & 7] = qd[(size_t)(qb * 16 + (tid >> 3)) * K_LCP + (tid & 7)];
  __syncthreads();
  for (int key = tid; key < T_DIM; key += 256) {
    float kv[K_LCP];
    *(float4*)&kv[0] = *(const float4*)(kd + (size_t)key * K_LCP);
    *(float4*)&kv[4] = *(const float4*)(kd + (size_t)key * K_LCP + 4);
    int any = 0;
#pragma unroll
    for (int ql = 0; ql < 16; ++ql) {
      int qg = qb * 16 + ql;
      if (key > qg) continue;
      int lcp = 0;
#pragma unroll
      for (int jj = 0; jj < K_LCP; ++jj) {
        if (qds[ql][jj] == kv[jj]) lcp++;
        else break;
      }
      if (lcp >= K_LCP - 1) any = 1;
    }
    if (any) tm[key >> 6] = 1;  // benign race: same value
  }
  __syncthreads();
  if (tid < 32) tilemask[qb * 32 + tid] = tm[tid];
}

// ---------------- vtsum[kt][c] = sum over tile rows of v ------------------------
__global__ __launch_bounds__(256) void vtsum_kernel(const bf16* __restrict__ v,
                                                    float* __restrict__ vtsum) {
  const int kt = blockIdx.x;
  const int c4 = threadIdx.x * 4;
  f32x4 s = {0.f, 0.f, 0.f, 0.f};
  for (int r = 0; r < 64; ++r) {
    bf16x4 vv = *(const bf16x4*)(v + (size_t)(kt * 64 + r) * C_DIM + c4);
    s[0] += (float)vv[0];
    s[1] += (float)vv[1];
    s[2] += (float)vv[2];
    s[3] += (float)vv[3];
  }
  *(f32x4*)(vtsum + (size_t)kt * C_DIM + c4) = s;
}

// ---------------- flash attention w/ precomputed tile mask + tile V sums --------
#define QT 16
#define KT 64

__global__ __launch_bounds__(256) void attn2(
    const bf16* __restrict__ q, const bf16* __restrict__ k,
    const bf16* __restrict__ v, const float* __restrict__ qd,
    const float* __restrict__ kd, const float* __restrict__ vtsum,
    const int* __restrict__ tilemask, bf16* __restrict__ y) {
  const int h = blockIdx.y;
  const int qb = blockIdx.x;
  const int q0 = qb * QT;
  const int tid = threadIdx.x;

  __shared__ float qs[QT][HD_DIM];
  __shared__ float qds[QT][K_LCP];
  __shared__ float ks[KT][HD_DIM];
  __shared__ float vs[KT][HD_DIM];
  __shared__ float kds[KT][K_LCP];
  __shared__ float sc[QT][KT + 4];

  {
    int r = tid >> 4, c4 = (tid & 15) * 4;
    bf16x4 t4 = *(const bf16x4*)(q + (size_t)(q0 + r) * C_DIM + h * HD_DIM + c4);
    qs[r][c4 + 0] = (float)t4[0] * 0.125f;
    qs[r][c4 + 1] = (float)t4[1] * 0.125f;
    qs[r][c4 + 2] = (float)t4[2] * 0.125f;
    qs[r][c4 + 3] = (float)t4[3] * 0.125f;
    if (tid < QT * K_LCP)
      qds[tid >> 3][tid & 7] = qd[(size_t)(q0 + (tid >> 3)) * K_LCP + (tid & 7)];
  }
  __syncthreads();

  const int q_l = tid >> 4;
  const int sub = tid & 15;
  float m = -INFINITY;
  float l = 0.f;
  float acc[4] = {0.f, 0.f, 0.f, 0.f};

  for (int kt = 0; kt < T_DIM / KT; ++kt) {
    if (!tilemask[qb * 32 + kt]) {
      // exact fast path: all scores in tile are NEG
      if (m <= NEG_VAL) {
        m = NEG_VAL;
        l += (float)KT;
        f32x4 vt = *(const f32x4*)(vtsum + (size_t)kt * C_DIM + h * HD_DIM + sub * 4);
        acc[0] += vt[0];
        acc[1] += vt[1];
        acc[2] += vt[2];
        acc[3] += vt[3];
      }
      continue;
    }
    // slow path (block-uniform branch)
    const int k0 = kt * KT;
    __syncthreads();  // protect previous slow tile's LDS reads
#pragma unroll
    for (int it = 0; it < 4; ++it) {
      int i = tid + it * 256;
      int row = i >> 4, c4 = (i & 15) * 4;
      bf16x4 kv = *(const bf16x4*)(k + (size_t)(k0 + row) * C_DIM + h * HD_DIM + c4);
      bf16x4 vv = *(const bf16x4*)(v + (size_t)(k0 + row) * C_DIM + h * HD_DIM + c4);
      ks[row][c4 + 0] = (float)kv[0];
      ks[row][c4 + 1] = (float)kv[1];
      ks[row][c4 + 2] = (float)kv[2];
      ks[row][c4 + 3] = (float)kv[3];
      vs[row][c4 + 0] = (float)vv[0];
      vs[row][c4 + 1] = (float)vv[1];
      vs[row][c4 + 2] = (float)vv[2];
      vs[row][c4 + 3] = (float)vv[3];
    }
#pragma unroll
    for (int it = 0; it < 2; ++it) {
      int i = tid + it * 256;
      kds[i >> 3][i & 7] = kd[(size_t)(k0 + (i >> 3)) * K_LCP + (i & 7)];
    }
    __syncthreads();

    const int kb = sub * 4;
    bool msk[4];
#pragma unroll
    for (int j = 0; j < 4; ++j) {
      int kg = k0 + kb + j;
      int lcp = 0;
#pragma unroll
      for (int jj = 0; jj < K_LCP; ++jj) {
        if (qds[q_l][jj] == kds[kb + j][jj]) lcp++;
        else break;
      }
      msk[j] = (lcp >= K_LCP - 1) && (kg <= q0 + q_l);
    }
    float s[4] = {0.f, 0.f, 0.f, 0.f};
#pragma unroll
    for (int d4 = 0; d4 < 16; ++d4) {
      float4 q4 = *(const float4*)&qs[q_l][d4 * 4];
#pragma unroll
      for (int j = 0; j < 4; ++j) {
        float4 k4 = *(const float4*)&ks[kb + j][d4 * 4];
        s[j] = fmaf(q4.x, k4.x, s[j]);
        s[j] = fmaf(q4.y, k4.y, s[j]);
        s[j] = fmaf(q4.z, k4.z, s[j]);
        s[j] = fmaf(q4.w, k4.w, s[j]);
      }
    }
    float tmax = NEG_VAL;
#pragma unroll
    for (int j = 0; j < 4; ++j) {
      s[j] = msk[j] ? s[j] : NEG_VAL;
      tmax = fmaxf(tmax, s[j]);
    }
#pragma unroll
    for (int off = 1; off < 16; off <<= 1) tmax = fmaxf(tmax, __shfl_xor(tmax, off));
    float m_new = fmaxf(m, tmax);
    float alpha = expf(m - m_new);
    float lsum = 0.f;
#pragma unroll
    for (int j = 0; j < 4; ++j) {
      float p = expf(s[j] - m_new);
      sc[q_l][kb + j] = p;
      lsum += p;
    }
#pragma unroll
    for (int off = 1; off < 16; off <<= 1) lsum += __shfl_xor(lsum, off);
    l = l * alpha + lsum;
    m = m_new;
    acc[0] *= alpha;
    acc[1] *= alpha;
    acc[2] *= alpha;
    acc[3] *= alpha;
    __syncthreads();
#pragma unroll 8
    for (int kk = 0; kk < KT; ++kk) {
      float w = sc[q_l][kk];
      const float4 v4 = *(const float4*)&vs[kk][sub * 4];
      acc[0] = fmaf(w, v4.x, acc[0]);
      acc[1] = fmaf(w, v4.y, acc[1]);
      acc[2] = fmaf(w, v4.z, acc[2]);
      acc[3] = fmaf(w, v4.w, acc[3]);
    }
  }

  const float inv_l = 1.0f / l;
  bf16x4 o = {(bf16)(acc[0] * inv_l), (bf16)(acc[1] * inv_l),
              (bf16)(acc[2] * inv_l), (bf16)(acc[3] * inv_l)};
  *(bf16x4*)(y + (size_t)(q0 + q_l) * C_DIM + h * HD_DIM + sub * 4) = o;
}

extern "C" void kernel_launch(void* const* d_in, const int* in_sizes, int n_in,
                              void* d_out, int out_size, void* d_ws, size_t ws_size,
                              hipStream_t stream) {
  const float* x = (const float*)d_in[0];
  const float* cosT = (const float*)d_in[1];
  const float* sinT = (const float*)d_in[2];
  const float* Wq = (const float*)d_in[3];
  const float* Wk = (const float*)d_in[4];
  const float* Wv = (const float*)d_in[5];
  const float* Wproj = (const float*)d_in[6];
  const float* Wdq = (const float*)d_in[7];
  const float* Wdk = (const float*)d_in[8];
  float* out = (float*)d_out;

  char* ws = (char*)d_ws;
  const size_t TC2 = (size_t)T_DIM * C_DIM * 2;   // bf16 [T][C] bytes
  const size_t CC2 = (size_t)C_DIM * C_DIM * 2;   // bf16 [C][C] bytes
  bf16* xb = (bf16*)(ws + 0);                     // 4 MB (aliased as yb later)
  bf16* wqt = (bf16*)(ws + TC2);
  bf16* wkt = (bf16*)(ws + TC2 + CC2);
  bf16* wvt = (bf16*)(ws + TC2 + 2 * CC2);
  bf16* wpt = (bf16*)(ws + TC2 + 3 * CC2);
  bf16* qb = (bf16*)(ws + TC2 + 4 * CC2);
  bf16* kb = (bf16*)(ws + 2 * TC2 + 4 * CC2);
  bf16* vb = (bf16*)(ws + 3 * TC2 + 4 * CC2);
  char* p2 = ws + 4 * TC2 + 4 * CC2;
  float* qd = (float*)p2;
  float* kd = (float*)(p2 + (size_t)T_DIM * K_LCP * 4);
  float* vtsum = (float*)(p2 + 2 * (size_t)T_DIM * K_LCP * 4);
  int* tilemask = (int*)(p2 + 2 * (size_t)T_DIM * K_LCP * 4 + 32 * C_DIM * 4);
  bf16* yb = xb;  // x (bf16) is dead after the QKV GEMM

  convert_x<<<T_DIM * C_DIM / 1024, 256, 0, stream>>>(x, xb);
  transpose_w<<<dim3(16, 16, 4), 256, 0, stream>>>(Wq, Wk, Wv, Wproj, wqt, wkt,
                                                   wvt, wpt);
  gemm_bf16<<<dim3(C_DIM / TN, T_DIM / TM, 3), 256, 0, stream>>>(
      xb, wqt, wkt, wvt, qb, kb, vb, T_DIM, C_DIM, C_DIM, 1);
  qdkd_kernel<<<T_DIM, 128, 0, stream>>>(x, Wdq, Wdk, qd, kd);
  rope_rms<<<dim3(T_DIM * H_NUM / 8, 2), 256, 0, stream>>>(qb, kb, cosT, sinT);
  tilemask_kernel<<<T_DIM / QT, 256, 0, stream>>>(qd, kd, tilemask);
  vtsum_kernel<<<T_DIM / KT, 256, 0, stream>>>(vb, vtsum);
  attn2<<<dim3(T_DIM / QT, H_NUM), 256, 0, stream>>>(qb, kb, vb, qd, kd, vtsum,
                                                     tilemask, yb);
  gemm_bf16<<<dim3(C_DIM / TN, T_DIM / TM, 1), 256, 0, stream>>>(
      yb, wpt, wpt, wpt, out, out, out, T_DIM, C_DIM, C_DIM, 0);
}

// Round 3
// 172.601 us; speedup vs baseline: 3.4629x; 1.3971x over previous
//
#include <hip/hip_runtime.h>
#include <math.h>

#define T_DIM 2048
#define C_DIM 1024
#define H_NUM 16
#define HD_DIM 64
#define K_LCP 8
#define NEG_VAL -1.0e9f

typedef __bf16 bf16;
typedef __bf16 bf16x4 __attribute__((ext_vector_type(4)));
typedef __bf16 bf16x8 __attribute__((ext_vector_type(8)));
typedef float f32x4 __attribute__((ext_vector_type(4)));

// ---------------- convert x fp32 -> bf16 ----------------
__global__ __launch_bounds__(256) void convert_x(const float* __restrict__ x,
                                                 bf16* __restrict__ xb) {
  int i = blockIdx.x * 256 + threadIdx.x;
  float4 f = ((const float4*)x)[i];
  bf16x4 o = {(bf16)f.x, (bf16)f.y, (bf16)f.z, (bf16)f.w};
  ((bf16x4*)xb)[i] = o;
}

// ---------------- transpose + convert weights: W[K][N] fp32 -> Wt[N][K] bf16 ----
__global__ __launch_bounds__(256) void transpose_w(const float* __restrict__ W0,
                                                   const float* __restrict__ W1,
                                                   const float* __restrict__ W2,
                                                   const float* __restrict__ W3,
                                                   bf16* __restrict__ O0,
                                                   bf16* __restrict__ O1,
                                                   bf16* __restrict__ O2,
                                                   bf16* __restrict__ O3) {
  const float* W = (blockIdx.z == 0) ? W0 : (blockIdx.z == 1) ? W1
                   : (blockIdx.z == 2) ? W2 : W3;
  bf16* O = (blockIdx.z == 0) ? O0 : (blockIdx.z == 1) ? O1
            : (blockIdx.z == 2) ? O2 : O3;
  __shared__ bf16 tile[64][65];
  const int bk = blockIdx.y * 64;
  const int bn = blockIdx.x * 64;
  const int r = threadIdx.x >> 2;
  const int c0 = (threadIdx.x & 3) * 16;
  const float* src = W + (size_t)(bk + r) * C_DIM + bn + c0;
#pragma unroll
  for (int t = 0; t < 16; t += 4) {
    float4 f = *(const float4*)(src + t);
    tile[r][c0 + t + 0] = (bf16)f.x;
    tile[r][c0 + t + 1] = (bf16)f.y;
    tile[r][c0 + t + 2] = (bf16)f.z;
    tile[r][c0 + t + 3] = (bf16)f.w;
  }
  __syncthreads();
  bf16* dst = O + (size_t)(bn + r) * C_DIM + bk + c0;
#pragma unroll
  for (int t = 0; t < 16; ++t) dst[t] = tile[c0 + t][r];
}

// ------- bf16 MFMA GEMM (m97 structure, global_load_lds width=16) ---------------
// C[M][128-col tiles] = A[M][K] * Bt[N][K]^T ; TMt in {128, 64}
template <int TMt, int MI, int NA>
__global__ __launch_bounds__(256) void gemm_bf16(
    const bf16* __restrict__ A, const bf16* __restrict__ Bt0,
    const bf16* __restrict__ Bt1, const bf16* __restrict__ Bt2, void* C0,
    void* C1, void* C2, int N, int Kd, int bf16_out) {
  const bf16* Bt = (blockIdx.z == 0) ? Bt0 : (blockIdx.z == 1) ? Bt1 : Bt2;
  __shared__ __align__(16) bf16 As[TMt * 32];
  __shared__ __align__(16) bf16 Bs[128 * 32];
  const int tid = threadIdx.x;
  const int bm = blockIdx.y * TMt;
  const int bn = blockIdx.x * 128;
  const int wave = tid >> 6, lane = tid & 63;
  const int lr = lane >> 2;            // row within a 16-row staging instr
  const int lc = (lane & 3) * 8;       // element col within 32
  bf16* gA = (bf16*)(A + (size_t)(bm + wave * 16 * NA + lr) * Kd + lc);
  bf16* gB = (bf16*)(Bt + (size_t)(bn + wave * 32 + lr) * Kd + lc);
  bf16* lA = As + wave * 512 * NA;     // wave-uniform LDS base
  bf16* lB = Bs + wave * 1024;
  const int wr = (wave >> 1) * (MI * 16);
  const int wc = (wave & 1) * 64;
  const int fm = lane & 15;
  const int fk = (lane >> 4) * 8;

  f32x4 acc[MI][4] = {};
  for (int k0 = 0; k0 < Kd; k0 += 32) {
    __syncthreads();
#pragma unroll
    for (int u = 0; u < NA; ++u)
      __builtin_amdgcn_global_load_lds(
          (__attribute__((address_space(1))) void*)(gA + (size_t)u * 16 * Kd + k0),
          (__attribute__((address_space(3))) void*)(lA + u * 512), 16, 0, 0);
#pragma unroll
    for (int u = 0; u < 2; ++u)
      __builtin_amdgcn_global_load_lds(
          (__attribute__((address_space(1))) void*)(gB + (size_t)u * 16 * Kd + k0),
          (__attribute__((address_space(3))) void*)(lB + u * 512), 16, 0, 0);
    __syncthreads();
    bf16x8 af[MI], bfr[4];
#pragma unroll
    for (int i = 0; i < MI; ++i)
      af[i] = *(const bf16x8*)(As + (size_t)(wr + i * 16 + fm) * 32 + fk);
#pragma unroll
    for (int j = 0; j < 4; ++j)
      bfr[j] = *(const bf16x8*)(Bs + (size_t)(wc + j * 16 + fm) * 32 + fk);
#pragma unroll
    for (int i = 0; i < MI; ++i)
#pragma unroll
      for (int j = 0; j < 4; ++j)
        acc[i][j] = __builtin_amdgcn_mfma_f32_16x16x32_bf16(af[i], bfr[j],
                                                            acc[i][j], 0, 0, 0);
  }
  const int cq = (lane >> 4) * 4;
  if (bf16_out) {
    bf16* C = (bf16*)((blockIdx.z == 0) ? C0 : (blockIdx.z == 1) ? C1 : C2);
#pragma unroll
    for (int i = 0; i < MI; ++i)
#pragma unroll
      for (int r = 0; r < 4; ++r) {
        size_t base = (size_t)(bm + wr + i * 16 + cq + r) * N + bn + wc + fm;
#pragma unroll
        for (int j = 0; j < 4; ++j) C[base + j * 16] = (bf16)acc[i][j][r];
      }
  } else {
    float* C = (float*)((blockIdx.z == 0) ? C0 : (blockIdx.z == 1) ? C1 : C2);
#pragma unroll
    for (int i = 0; i < MI; ++i)
#pragma unroll
      for (int r = 0; r < 4; ++r) {
        size_t base = (size_t)(bm + wr + i * 16 + cq + r) * N + bn + wc + fm;
#pragma unroll
        for (int j = 0; j < 4; ++j) C[base + j * 16] = acc[i][j][r];
      }
  }
}

// ---------------- qd,kd: one wave per row, lane-parallel over C -----------------
__global__ __launch_bounds__(256) void qdkd2(const float* __restrict__ x,
                                             const float* __restrict__ Wdq,
                                             const float* __restrict__ Wdk,
                                             float* __restrict__ qd,
                                             float* __restrict__ kd) {
  const int wave = threadIdx.x >> 6, lane = threadIdx.x & 63;
  const int t = blockIdx.x * 4 + wave;
  const float* xp = x + (size_t)t * C_DIM;
  float aq[8] = {}, ak[8] = {};
#pragma unroll
  for (int i = 0; i < 16; ++i) {
    const int c = i * 64 + lane;
    float xv = xp[c];
    float4 wq0 = *(const float4*)(Wdq + (size_t)c * K_LCP);
    float4 wq1 = *(const float4*)(Wdq + (size_t)c * K_LCP + 4);
    float4 wk0 = *(const float4*)(Wdk + (size_t)c * K_LCP);
    float4 wk1 = *(const float4*)(Wdk + (size_t)c * K_LCP + 4);
    aq[0] = fmaf(xv, wq0.x, aq[0]); aq[1] = fmaf(xv, wq0.y, aq[1]);
    aq[2] = fmaf(xv, wq0.z, aq[2]); aq[3] = fmaf(xv, wq0.w, aq[3]);
    aq[4] = fmaf(xv, wq1.x, aq[4]); aq[5] = fmaf(xv, wq1.y, aq[5]);
    aq[6] = fmaf(xv, wq1.z, aq[6]); aq[7] = fmaf(xv, wq1.w, aq[7]);
    ak[0] = fmaf(xv, wk0.x, ak[0]); ak[1] = fmaf(xv, wk0.y, ak[1]);
    ak[2] = fmaf(xv, wk0.z, ak[2]); ak[3] = fmaf(xv, wk0.w, ak[3]);
    ak[4] = fmaf(xv, wk1.x, ak[4]); ak[5] = fmaf(xv, wk1.y, ak[5]);
    ak[6] = fmaf(xv, wk1.z, ak[6]); ak[7] = fmaf(xv, wk1.w, ak[7]);
  }
#pragma unroll
  for (int j = 0; j < 8; ++j) {
#pragma unroll
    for (int off = 32; off >= 1; off >>= 1) {
      aq[j] += __shfl_xor(aq[j], off);
      ak[j] += __shfl_xor(ak[j], off);
    }
  }
  if (lane == 0) {
    *(float4*)(qd + (size_t)t * K_LCP) = make_float4(aq[0], aq[1], aq[2], aq[3]);
    *(float4*)(qd + (size_t)t * K_LCP + 4) = make_float4(aq[4], aq[5], aq[6], aq[7]);
    *(float4*)(kd + (size_t)t * K_LCP) = make_float4(ak[0], ak[1], ak[2], ak[3]);
    *(float4*)(kd + (size_t)t * K_LCP + 4) = make_float4(ak[4], ak[5], ak[6], ak[7]);
  }
}

// ---------------- RoPE + RMS-norm on bf16 q,k in place --------------------------
__global__ __launch_bounds__(256) void rope_rms(bf16* __restrict__ qp,
                                                bf16* __restrict__ kp,
                                                const float* __restrict__ cosT,
                                                const float* __restrict__ sinT) {
  const int row = blockIdx.x * 8 + (threadIdx.x >> 5);
  const int i = threadIdx.x & 31;
  bf16* base = blockIdx.y ? kp : qp;
  const int t = row >> 4;
  bf16* p = base + (size_t)row * HD_DIM;
  float x1 = (float)p[i], x2 = (float)p[i + 32];
  float c = cosT[(size_t)t * 32 + i], s = sinT[(size_t)t * 32 + i];
  float o1 = x1 * c - x2 * s;
  float o2 = x1 * s + x2 * c;
  float sq = o1 * o1 + o2 * o2;
#pragma unroll
  for (int m = 1; m < 32; m <<= 1) sq += __shfl_xor(sq, m);
  float r = 1.0f / sqrtf(sq * (1.0f / 64.0f) + 1e-6f);
  p[i] = (bf16)(o1 * r);
  p[i + 32] = (bf16)(o2 * r);
}

// -------- tilemask[qb][kt] + allmask[qb] ----------------------------------------
__global__ __launch_bounds__(256) void tilemask_kernel(const float* __restrict__ qd,
                                                       const float* __restrict__ kd,
                                                       int* __restrict__ tilemask,
                                                       int* __restrict__ allmask) {
  const int qb = blockIdx.x;
  __shared__ float qds[16][K_LCP];
  __shared__ int tm[32];
  const int tid = threadIdx.x;
  if (tid < 32) tm[tid] = 0;
  if (tid < 16 * K_LCP)
    qds[tid >> 3][tid & 7] = qd[(size_t)(qb * 16 + (tid >> 3)) * K_LCP + (tid & 7)];
  __syncthreads();
  for (int key = tid; key < T_DIM; key += 256) {
    float kv[K_LCP];
    *(float4*)&kv[0] = *(const float4*)(kd + (size_t)key * K_LCP);
    *(float4*)&kv[4] = *(const float4*)(kd + (size_t)key * K_LCP + 4);
    int any = 0;
#pragma unroll
    for (int ql = 0; ql < 16; ++ql) {
      int qg = qb * 16 + ql;
      if (key > qg) continue;
      int lcp = 0;
#pragma unroll
      for (int jj = 0; jj < K_LCP; ++jj) {
        if (qds[ql][jj] == kv[jj]) lcp++;
        else break;
      }
      if (lcp >= K_LCP - 1) any = 1;
    }
    if (any) tm[key >> 6] = 1;  // benign race: same value
  }
  __syncthreads();
  if (tid < 32) tilemask[qb * 32 + tid] = tm[tid];
  if (tid == 0) {
    int any = 0;
#pragma unroll
    for (int i = 0; i < 32; ++i) any |= tm[i];
    allmask[qb] = !any;
  }
}

// ---------------- vtsum[kt][c] = sum over tile rows of v ------------------------
__global__ __launch_bounds__(256) void vtsum_kernel(const bf16* __restrict__ v,
                                                    float* __restrict__ vtsum) {
  const int kt = blockIdx.x;
  const int col = blockIdx.y * 256 + threadIdx.x;
  float s = 0.f;
#pragma unroll 8
  for (int r = 0; r < 64; ++r) s += (float)v[(size_t)(kt * 64 + r) * C_DIM + col];
  vtsum[(size_t)kt * C_DIM + col] = s;
}

// ---------------- vmean[c] = sum_kt vtsum[kt][c] / T ----------------------------
__global__ __launch_bounds__(256) void vmean_kernel(const float* __restrict__ vtsum,
                                                    float* __restrict__ vmean) {
  const int c = blockIdx.x * 256 + threadIdx.x;
  float s = 0.f;
#pragma unroll
  for (int kt = 0; kt < 32; ++kt) s += vtsum[(size_t)kt * C_DIM + c];
  vmean[c] = s * (1.0f / 2048.0f);
}

// ---------------- flash attention w/ tile mask, V sums, all-masked exit ---------
#define QT 16
#define KT 64

__global__ __launch_bounds__(256) void attn2(
    const bf16* __restrict__ q, const bf16* __restrict__ k,
    const bf16* __restrict__ v, const float* __restrict__ qd,
    const float* __restrict__ kd, const float* __restrict__ vtsum,
    const float* __restrict__ vmean, const int* __restrict__ tilemask,
    const int* __restrict__ allmask, bf16* __restrict__ y) {
  const int h = blockIdx.y;
  const int qb = blockIdx.x;
  const int q0 = qb * QT;
  const int tid = threadIdx.x;
  const int q_l = tid >> 4;
  const int sub = tid & 15;

  if (allmask[qb]) {
    // every score in these rows is NEG -> softmax uniform over all T keys
    f32x4 vm = *(const f32x4*)(vmean + h * HD_DIM + sub * 4);
    bf16x4 o = {(bf16)vm[0], (bf16)vm[1], (bf16)vm[2], (bf16)vm[3]};
    *(bf16x4*)(y + (size_t)(q0 + q_l) * C_DIM + h * HD_DIM + sub * 4) = o;
    return;
  }

  __shared__ float qs[QT][HD_DIM];
  __shared__ float qds[QT][K_LCP];
  __shared__ float ks[KT][HD_DIM];
  __shared__ float vs[KT][HD_DIM];
  __shared__ float kds[KT][K_LCP];
  __shared__ float sc[QT][KT + 4];

  {
    int r = tid >> 4, c4 = (tid & 15) * 4;
    bf16x4 t4 = *(const bf16x4*)(q + (size_t)(q0 + r) * C_DIM + h * HD_DIM + c4);
    qs[r][c4 + 0] = (float)t4[0] * 0.125f;
    qs[r][c4 + 1] = (float)t4[1] * 0.125f;
    qs[r][c4 + 2] = (float)t4[2] * 0.125f;
    qs[r][c4 + 3] = (float)t4[3] * 0.125f;
    if (tid < QT * K_LCP)
      qds[tid >> 3][tid & 7] = qd[(size_t)(q0 + (tid >> 3)) * K_LCP + (tid & 7)];
  }
  __syncthreads();

  float m = -INFINITY;
  float l = 0.f;
  float acc[4] = {0.f, 0.f, 0.f, 0.f};

  for (int kt = 0; kt < T_DIM / KT; ++kt) {
    if (!tilemask[qb * 32 + kt]) {
      if (m <= NEG_VAL) {
        m = NEG_VAL;
        l += (float)KT;
        f32x4 vt = *(const f32x4*)(vtsum + (size_t)kt * C_DIM + h * HD_DIM + sub * 4);
        acc[0] += vt[0];
        acc[1] += vt[1];
        acc[2] += vt[2];
        acc[3] += vt[3];
      }
      continue;
    }
    const int k0 = kt * KT;
    __syncthreads();
#pragma unroll
    for (int it = 0; it < 4; ++it) {
      int i = tid + it * 256;
      int row = i >> 4, c4 = (i & 15) * 4;
      bf16x4 kv = *(const bf16x4*)(k + (size_t)(k0 + row) * C_DIM + h * HD_DIM + c4);
      bf16x4 vv = *(const bf16x4*)(v + (size_t)(k0 + row) * C_DIM + h * HD_DIM + c4);
      ks[row][c4 + 0] = (float)kv[0];
      ks[row][c4 + 1] = (float)kv[1];
      ks[row][c4 + 2] = (float)kv[2];
      ks[row][c4 + 3] = (float)kv[3];
      vs[row][c4 + 0] = (float)vv[0];
      vs[row][c4 + 1] = (float)vv[1];
      vs[row][c4 + 2] = (float)vv[2];
      vs[row][c4 + 3] = (float)vv[3];
    }
#pragma unroll
    for (int it = 0; it < 2; ++it) {
      int i = tid + it * 256;
      kds[i >> 3][i & 7] = kd[(size_t)(k0 + (i >> 3)) * K_LCP + (i & 7)];
    }
    __syncthreads();

    const int kb = sub * 4;
    bool msk[4];
#pragma unroll
    for (int j = 0; j < 4; ++j) {
      int kg = k0 + kb + j;
      int lcp = 0;
#pragma unroll
      for (int jj = 0; jj < K_LCP; ++jj) {
        if (qds[q_l][jj] == kds[kb + j][jj]) lcp++;
        else break;
      }
      msk[j] = (lcp >= K_LCP - 1) && (kg <= q0 + q_l);
    }
    float s[4] = {0.f, 0.f, 0.f, 0.f};
#pragma unroll
    for (int d4 = 0; d4 < 16; ++d4) {
      float4 q4 = *(const float4*)&qs[q_l][d4 * 4];
#pragma unroll
      for (int j = 0; j < 4; ++j) {
        float4 k4 = *(const float4*)&ks[kb + j][d4 * 4];
        s[j] = fmaf(q4.x, k4.x, s[j]);
        s[j] = fmaf(q4.y, k4.y, s[j]);
        s[j] = fmaf(q4.z, k4.z, s[j]);
        s[j] = fmaf(q4.w, k4.w, s[j]);
      }
    }
    float tmax = NEG_VAL;
#pragma unroll
    for (int j = 0; j < 4; ++j) {
      s[j] = msk[j] ? s[j] : NEG_VAL;
      tmax = fmaxf(tmax, s[j]);
    }
#pragma unroll
    for (int off = 1; off < 16; off <<= 1) tmax = fmaxf(tmax, __shfl_xor(tmax, off));
    float m_new = fmaxf(m, tmax);
    float alpha = expf(m - m_new);
    float lsum = 0.f;
#pragma unroll
    for (int j = 0; j < 4; ++j) {
      float p = expf(s[j] - m_new);
      sc[q_l][kb + j] = p;
      lsum += p;
    }
#pragma unroll
    for (int off = 1; off < 16; off <<= 1) lsum += __shfl_xor(lsum, off);
    l = l * alpha + lsum;
    m = m_new;
    acc[0] *= alpha;
    acc[1] *= alpha;
    acc[2] *= alpha;
    acc[3] *= alpha;
    __syncthreads();
#pragma unroll 8
    for (int kk = 0; kk < KT; ++kk) {
      float w = sc[q_l][kk];
      const float4 v4 = *(const float4*)&vs[kk][sub * 4];
      acc[0] = fmaf(w, v4.x, acc[0]);
      acc[1] = fmaf(w, v4.y, acc[1]);
      acc[2] = fmaf(w, v4.z, acc[2]);
      acc[3] = fmaf(w, v4.w, acc[3]);
    }
  }

  const float inv_l = 1.0f / l;
  bf16x4 o = {(bf16)(acc[0] * inv_l), (bf16)(acc[1] * inv_l),
              (bf16)(acc[2] * inv_l), (bf16)(acc[3] * inv_l)};
  *(bf16x4*)(y + (size_t)(q0 + q_l) * C_DIM + h * HD_DIM + sub * 4) = o;
}

extern "C" void kernel_launch(void* const* d_in, const int* in_sizes, int n_in,
                              void* d_out, int out_size, void* d_ws, size_t ws_size,
                              hipStream_t stream) {
  const float* x = (const float*)d_in[0];
  const float* cosT = (const float*)d_in[1];
  const float* sinT = (const float*)d_in[2];
  const float* Wq = (const float*)d_in[3];
  const float* Wk = (const float*)d_in[4];
  const float* Wv = (const float*)d_in[5];
  const float* Wproj = (const float*)d_in[6];
  const float* Wdq = (const float*)d_in[7];
  const float* Wdk = (const float*)d_in[8];
  float* out = (float*)d_out;

  char* ws = (char*)d_ws;
  const size_t TC2 = (size_t)T_DIM * C_DIM * 2;
  const size_t CC2 = (size_t)C_DIM * C_DIM * 2;
  bf16* xb = (bf16*)(ws + 0);
  bf16* wqt = (bf16*)(ws + TC2);
  bf16* wkt = (bf16*)(ws + TC2 + CC2);
  bf16* wvt = (bf16*)(ws + TC2 + 2 * CC2);
  bf16* wpt = (bf16*)(ws + TC2 + 3 * CC2);
  bf16* qb = (bf16*)(ws + TC2 + 4 * CC2);
  bf16* kb = (bf16*)(ws + 2 * TC2 + 4 * CC2);
  bf16* vb = (bf16*)(ws + 3 * TC2 + 4 * CC2);
  char* p2 = ws + 4 * TC2 + 4 * CC2;
  float* qd = (float*)p2;
  float* kd = (float*)(p2 + (size_t)T_DIM * K_LCP * 4);
  float* vtsum = (float*)(p2 + 2 * (size_t)T_DIM * K_LCP * 4);
  float* vmean = (float*)(p2 + 2 * (size_t)T_DIM * K_LCP * 4 + 32 * C_DIM * 4);
  int* tilemask = (int*)(p2 + 2 * (size_t)T_DIM * K_LCP * 4 + 33 * C_DIM * 4);
  int* allmask = tilemask + (T_DIM / QT) * 32;
  bf16* yb = xb;  // x (bf16) is dead after the QKV GEMM

  convert_x<<<T_DIM * C_DIM / 1024, 256, 0, stream>>>(x, xb);
  transpose_w<<<dim3(16, 16, 4), 256, 0, stream>>>(Wq, Wk, Wv, Wproj, wqt, wkt,
                                                   wvt, wpt);
  gemm_bf16<128, 4, 2><<<dim3(C_DIM / 128, T_DIM / 128, 3), 256, 0, stream>>>(
      xb, wqt, wkt, wvt, qb, kb, vb, C_DIM, C_DIM, 1);
  qdkd2<<<T_DIM / 4, 256, 0, stream>>>(x, Wdq, Wdk, qd, kd);
  rope_rms<<<dim3(T_DIM * H_NUM / 8, 2), 256, 0, stream>>>(qb, kb, cosT, sinT);
  tilemask_kernel<<<T_DIM / QT, 256, 0, stream>>>(qd, kd, tilemask, allmask);
  vtsum_kernel<<<dim3(T_DIM / KT, 4), 256, 0, stream>>>(vb, vtsum);
  vmean_kernel<<<4, 256, 0, stream>>>(vtsum, vmean);
  attn2<<<dim3(T_DIM / QT, H_NUM), 256, 0, stream>>>(
      qb, kb, vb, qd, kd, vtsum, vmean, tilemask, allmask, yb);
  gemm_bf16<64, 2, 1><<<dim3(C_DIM / 128, T_DIM / 64, 1), 256, 0, stream>>>(
      yb, wpt, wpt, wpt, out, out, out, C_DIM, C_DIM, 0);
}

// Round 4
// 170.360 us; speedup vs baseline: 3.5084x; 1.0132x over previous
//
#include <hip/hip_runtime.h>
#include <math.h>

#define T_DIM 2048
#define C_DIM 1024
#define H_NUM 16
#define HD_DIM 64
#define K_LCP 8
#define NEG_VAL -1.0e9f

typedef __bf16 bf16;
typedef __bf16 bf16x4 __attribute__((ext_vector_type(4)));
typedef __bf16 bf16x8 __attribute__((ext_vector_type(8)));
typedef float f32x4 __attribute__((ext_vector_type(4)));

// ------- convert x fp32->bf16 AND qd=x@Wdq, kd=x@Wdk (one wave per row) ---------
__global__ __launch_bounds__(256) void convert_qdkd(const float* __restrict__ x,
                                                    const float* __restrict__ Wdq,
                                                    const float* __restrict__ Wdk,
                                                    bf16* __restrict__ xb,
                                                    float* __restrict__ qd,
                                                    float* __restrict__ kd) {
  const int wave = threadIdx.x >> 6, lane = threadIdx.x & 63;
  const int t = blockIdx.x * 4 + wave;
  const float* xp = x + (size_t)t * C_DIM;
  bf16* xbp = xb + (size_t)t * C_DIM;
  float aq[8] = {}, ak[8] = {};
#pragma unroll
  for (int i = 0; i < 16; ++i) {
    const int c = i * 64 + lane;
    float xv = xp[c];
    xbp[c] = (bf16)xv;
    float4 wq0 = *(const float4*)(Wdq + (size_t)c * K_LCP);
    float4 wq1 = *(const float4*)(Wdq + (size_t)c * K_LCP + 4);
    float4 wk0 = *(const float4*)(Wdk + (size_t)c * K_LCP);
    float4 wk1 = *(const float4*)(Wdk + (size_t)c * K_LCP + 4);
    aq[0] = fmaf(xv, wq0.x, aq[0]); aq[1] = fmaf(xv, wq0.y, aq[1]);
    aq[2] = fmaf(xv, wq0.z, aq[2]); aq[3] = fmaf(xv, wq0.w, aq[3]);
    aq[4] = fmaf(xv, wq1.x, aq[4]); aq[5] = fmaf(xv, wq1.y, aq[5]);
    aq[6] = fmaf(xv, wq1.z, aq[6]); aq[7] = fmaf(xv, wq1.w, aq[7]);
    ak[0] = fmaf(xv, wk0.x, ak[0]); ak[1] = fmaf(xv, wk0.y, ak[1]);
    ak[2] = fmaf(xv, wk0.z, ak[2]); ak[3] = fmaf(xv, wk0.w, ak[3]);
    ak[4] = fmaf(xv, wk1.x, ak[4]); ak[5] = fmaf(xv, wk1.y, ak[5]);
    ak[6] = fmaf(xv, wk1.z, ak[6]); ak[7] = fmaf(xv, wk1.w, ak[7]);
  }
#pragma unroll
  for (int j = 0; j < 8; ++j) {
#pragma unroll
    for (int off = 32; off >= 1; off >>= 1) {
      aq[j] += __shfl_xor(aq[j], off);
      ak[j] += __shfl_xor(ak[j], off);
    }
  }
  if (lane == 0) {
    *(float4*)(qd + (size_t)t * K_LCP) = make_float4(aq[0], aq[1], aq[2], aq[3]);
    *(float4*)(qd + (size_t)t * K_LCP + 4) = make_float4(aq[4], aq[5], aq[6], aq[7]);
    *(float4*)(kd + (size_t)t * K_LCP) = make_float4(ak[0], ak[1], ak[2], ak[3]);
    *(float4*)(kd + (size_t)t * K_LCP + 4) = make_float4(ak[4], ak[5], ak[6], ak[7]);
  }
}

// ---------------- transpose + convert weights: W[K][N] fp32 -> Wt[N][K] bf16 ----
__global__ __launch_bounds__(256) void transpose_w(const float* __restrict__ W0,
                                                   const float* __restrict__ W1,
                                                   const float* __restrict__ W2,
                                                   const float* __restrict__ W3,
                                                   bf16* __restrict__ O0,
                                                   bf16* __restrict__ O1,
                                                   bf16* __restrict__ O2,
                                                   bf16* __restrict__ O3) {
  const float* W = (blockIdx.z == 0) ? W0 : (blockIdx.z == 1) ? W1
                   : (blockIdx.z == 2) ? W2 : W3;
  bf16* O = (blockIdx.z == 0) ? O0 : (blockIdx.z == 1) ? O1
            : (blockIdx.z == 2) ? O2 : O3;
  __shared__ bf16 tile[64][65];
  const int bk = blockIdx.y * 64;
  const int bn = blockIdx.x * 64;
  const int r = threadIdx.x >> 2;
  const int c0 = (threadIdx.x & 3) * 16;
  const float* src = W + (size_t)(bk + r) * C_DIM + bn + c0;
#pragma unroll
  for (int t = 0; t < 16; t += 4) {
    float4 f = *(const float4*)(src + t);
    tile[r][c0 + t + 0] = (bf16)f.x;
    tile[r][c0 + t + 1] = (bf16)f.y;
    tile[r][c0 + t + 2] = (bf16)f.z;
    tile[r][c0 + t + 3] = (bf16)f.w;
  }
  __syncthreads();
  bf16* dst = O + (size_t)(bn + r) * C_DIM + bk + c0;
#pragma unroll
  for (int t = 0; t < 16; ++t) dst[t] = tile[c0 + t][r];
}

// -------- tilemask[qb][kt] + allmask[qb] ----------------------------------------
__global__ __launch_bounds__(256) void tilemask_kernel(const float* __restrict__ qd,
                                                       const float* __restrict__ kd,
                                                       int* __restrict__ tilemask,
                                                       int* __restrict__ allmask) {
  const int qb = blockIdx.x;
  __shared__ float qds[16][K_LCP];
  __shared__ int tm[32];
  const int tid = threadIdx.x;
  if (tid < 32) tm[tid] = 0;
  if (tid < 16 * K_LCP)
    qds[tid >> 3][tid & 7] = qd[(size_t)(qb * 16 + (tid >> 3)) * K_LCP + (tid & 7)];
  __syncthreads();
  for (int key = tid; key < T_DIM; key += 256) {
    float kv[K_LCP];
    *(float4*)&kv[0] = *(const float4*)(kd + (size_t)key * K_LCP);
    *(float4*)&kv[4] = *(const float4*)(kd + (size_t)key * K_LCP + 4);
    int any = 0;
#pragma unroll
    for (int ql = 0; ql < 16; ++ql) {
      int qg = qb * 16 + ql;
      if (key > qg) continue;
      int lcp = 0;
#pragma unroll
      for (int jj = 0; jj < K_LCP; ++jj) {
        if (qds[ql][jj] == kv[jj]) lcp++;
        else break;
      }
      if (lcp >= K_LCP - 1) any = 1;
    }
    if (any) tm[key >> 6] = 1;  // benign race: same value
  }
  __syncthreads();
  if (tid < 32) tilemask[qb * 32 + tid] = tm[tid];
  if (tid == 0) {
    int any = 0;
#pragma unroll
    for (int i = 0; i < 32; ++i) any |= tm[i];
    allmask[qb] = !any;
  }
}

// -------- need flags per 128-row GEMM block -------------------------------------
__global__ __launch_bounds__(256) void need_kernel(const int* __restrict__ tilemask,
                                                   const int* __restrict__ allmask,
                                                   int* __restrict__ qneed,
                                                   int* __restrict__ kneed) {
  const int tid = threadIdx.x;
  __shared__ int km[32];
  if (tid < 32) {
    int o = 0;
    for (int qb = 0; qb < T_DIM / 16; ++qb) o |= tilemask[qb * 32 + tid];
    km[tid] = o;
  }
  if (tid >= 64 && tid < 80) {
    int i = tid - 64, o = 0;
#pragma unroll
    for (int j = 0; j < 8; ++j) o |= !allmask[i * 8 + j];
    qneed[i] = o;
  }
  __syncthreads();
  if (tid < 16) kneed[tid] = km[2 * tid] | km[2 * tid + 1];
}

// ------- bf16 MFMA GEMM (m97 structure) w/ fused RoPE+RMS epilogue & skip -------
// C[M][128-col tiles] = A[M][K] * Bt[N][K]^T ; TMt in {128, 64}
template <int TMt, int MI, int NA>
__global__ __launch_bounds__(256) void gemm_bf16(
    const bf16* __restrict__ A, const bf16* __restrict__ Bt0,
    const bf16* __restrict__ Bt1, const bf16* __restrict__ Bt2, void* C0,
    void* C1, void* C2, int N, int Kd, int bf16_out,
    const float* __restrict__ cosT, const float* __restrict__ sinT,
    const int* __restrict__ qneed, const int* __restrict__ kneed, int do_rope) {
  if (do_rope) {  // q/k slices: skip blocks whose outputs are never read
    if (blockIdx.z == 0 && !qneed[blockIdx.y]) return;
    if (blockIdx.z == 1 && !kneed[blockIdx.y]) return;
  }
  const bf16* Bt = (blockIdx.z == 0) ? Bt0 : (blockIdx.z == 1) ? Bt1 : Bt2;
  __shared__ __align__(16) bf16 As[TMt * 32];
  __shared__ __align__(16) bf16 Bs[128 * 32];
  const int tid = threadIdx.x;
  const int bm = blockIdx.y * TMt;
  const int bn = blockIdx.x * 128;
  const int wave = tid >> 6, lane = tid & 63;
  const int lr = lane >> 2;
  const int lc = (lane & 3) * 8;
  bf16* gA = (bf16*)(A + (size_t)(bm + wave * 16 * NA + lr) * Kd + lc);
  bf16* gB = (bf16*)(Bt + (size_t)(bn + wave * 32 + lr) * Kd + lc);
  bf16* lA = As + wave * 512 * NA;
  bf16* lB = Bs + wave * 1024;
  const int wr = (wave >> 1) * (MI * 16);
  const int wc = (wave & 1) * 64;
  const int fm = lane & 15;
  const int fk = (lane >> 4) * 8;

  f32x4 acc[MI][4] = {};
  for (int k0 = 0; k0 < Kd; k0 += 32) {
    __syncthreads();
#pragma unroll
    for (int u = 0; u < NA; ++u)
      __builtin_amdgcn_global_load_lds(
          (__attribute__((address_space(1))) void*)(gA + (size_t)u * 16 * Kd + k0),
          (__attribute__((address_space(3))) void*)(lA + u * 512), 16, 0, 0);
#pragma unroll
    for (int u = 0; u < 2; ++u)
      __builtin_amdgcn_global_load_lds(
          (__attribute__((address_space(1))) void*)(gB + (size_t)u * 16 * Kd + k0),
          (__attribute__((address_space(3))) void*)(lB + u * 512), 16, 0, 0);
    __syncthreads();
    bf16x8 af[MI], bfr[4];
#pragma unroll
    for (int i = 0; i < MI; ++i)
      af[i] = *(const bf16x8*)(As + (size_t)(wr + i * 16 + fm) * 32 + fk);
#pragma unroll
    for (int j = 0; j < 4; ++j)
      bfr[j] = *(const bf16x8*)(Bs + (size_t)(wc + j * 16 + fm) * 32 + fk);
#pragma unroll
    for (int i = 0; i < MI; ++i)
#pragma unroll
      for (int j = 0; j < 4; ++j)
        acc[i][j] = __builtin_amdgcn_mfma_f32_16x16x32_bf16(af[i], bfr[j],
                                                            acc[i][j], 0, 0, 0);
  }
  const int cq = (lane >> 4) * 4;
  if (do_rope && blockIdx.z < 2) {
    // wave's 64 cols == one head; RoPE pair (j, j+2); RMS over 64 via 16-lane xor
    bf16* C = (bf16*)((blockIdx.z == 0) ? C0 : C1);
#pragma unroll
    for (int i = 0; i < MI; ++i)
#pragma unroll
      for (int r = 0; r < 4; ++r) {
        const int t = bm + wr + i * 16 + cq + r;
        float c0 = cosT[(size_t)t * 32 + fm], s0 = sinT[(size_t)t * 32 + fm];
        float c1 = cosT[(size_t)t * 32 + 16 + fm], s1 = sinT[(size_t)t * 32 + 16 + fm];
        float a0 = acc[i][0][r], a1 = acc[i][1][r];
        float a2 = acc[i][2][r], a3 = acc[i][3][r];
        float o0 = a0 * c0 - a2 * s0, o2 = a0 * s0 + a2 * c0;
        float o1 = a1 * c1 - a3 * s1, o3 = a1 * s1 + a3 * c1;
        float ss = o0 * o0 + o1 * o1 + o2 * o2 + o3 * o3;
        ss += __shfl_xor(ss, 1);
        ss += __shfl_xor(ss, 2);
        ss += __shfl_xor(ss, 4);
        ss += __shfl_xor(ss, 8);
        float rn = 1.0f / sqrtf(ss * (1.0f / 64.0f) + 1e-6f);
        size_t base = (size_t)t * N + bn + wc + fm;
        C[base + 0] = (bf16)(o0 * rn);
        C[base + 16] = (bf16)(o1 * rn);
        C[base + 32] = (bf16)(o2 * rn);
        C[base + 48] = (bf16)(o3 * rn);
      }
  } else if (bf16_out) {
    bf16* C = (bf16*)((blockIdx.z == 0) ? C0 : (blockIdx.z == 1) ? C1 : C2);
#pragma unroll
    for (int i = 0; i < MI; ++i)
#pragma unroll
      for (int r = 0; r < 4; ++r) {
        size_t base = (size_t)(bm + wr + i * 16 + cq + r) * N + bn + wc + fm;
#pragma unroll
        for (int j = 0; j < 4; ++j) C[base + j * 16] = (bf16)acc[i][j][r];
      }
  } else {
    float* C = (float*)((blockIdx.z == 0) ? C0 : (blockIdx.z == 1) ? C1 : C2);
#pragma unroll
    for (int i = 0; i < MI; ++i)
#pragma unroll
      for (int r = 0; r < 4; ++r) {
        size_t base = (size_t)(bm + wr + i * 16 + cq + r) * N + bn + wc + fm;
#pragma unroll
        for (int j = 0; j < 4; ++j) C[base + j * 16] = acc[i][j][r];
      }
  }
}

// ---------------- vtsum[kt][c] = sum over tile rows of v ------------------------
__global__ __launch_bounds__(256) void vtsum_kernel(const bf16* __restrict__ v,
                                                    float* __restrict__ vtsum) {
  const int kt = blockIdx.x;
  const int col = blockIdx.y * 256 + threadIdx.x;
  float s = 0.f;
#pragma unroll 8
  for (int r = 0; r < 64; ++r) s += (float)v[(size_t)(kt * 64 + r) * C_DIM + col];
  vtsum[(size_t)kt * C_DIM + col] = s;
}

// ---------------- vmean[c] = sum_kt vtsum[kt][c] / T ----------------------------
__global__ __launch_bounds__(256) void vmean_kernel(const float* __restrict__ vtsum,
                                                    float* __restrict__ vmean) {
  const int c = blockIdx.x * 256 + threadIdx.x;
  float s = 0.f;
#pragma unroll
  for (int kt = 0; kt < 32; ++kt) s += vtsum[(size_t)kt * C_DIM + c];
  vmean[c] = s * (1.0f / 2048.0f);
}

// ---------------- flash attention w/ tile mask, V sums, all-masked exit ---------
#define QT 16
#define KT 64

__global__ __launch_bounds__(256) void attn2(
    const bf16* __restrict__ q, const bf16* __restrict__ k,
    const bf16* __restrict__ v, const float* __restrict__ qd,
    const float* __restrict__ kd, const float* __restrict__ vtsum,
    const float* __restrict__ vmean, const int* __restrict__ tilemask,
    const int* __restrict__ allmask, bf16* __restrict__ y) {
  const int h = blockIdx.y;
  const int qb = blockIdx.x;
  const int q0 = qb * QT;
  const int tid = threadIdx.x;
  const int q_l = tid >> 4;
  const int sub = tid & 15;

  if (allmask[qb]) {
    f32x4 vm = *(const f32x4*)(vmean + h * HD_DIM + sub * 4);
    bf16x4 o = {(bf16)vm[0], (bf16)vm[1], (bf16)vm[2], (bf16)vm[3]};
    *(bf16x4*)(y + (size_t)(q0 + q_l) * C_DIM + h * HD_DIM + sub * 4) = o;
    return;
  }

  __shared__ float qs[QT][HD_DIM];
  __shared__ float qds[QT][K_LCP];
  __shared__ float ks[KT][HD_DIM];
  __shared__ float vs[KT][HD_DIM];
  __shared__ float kds[KT][K_LCP];
  __shared__ float sc[QT][KT + 4];

  {
    int r = tid >> 4, c4 = (tid & 15) * 4;
    bf16x4 t4 = *(const bf16x4*)(q + (size_t)(q0 + r) * C_DIM + h * HD_DIM + c4);
    qs[r][c4 + 0] = (float)t4[0] * 0.125f;
    qs[r][c4 + 1] = (float)t4[1] * 0.125f;
    qs[r][c4 + 2] = (float)t4[2] * 0.125f;
    qs[r][c4 + 3] = (float)t4[3] * 0.125f;
    if (tid < QT * K_LCP)
      qds[tid >> 3][tid & 7] = qd[(size_t)(q0 + (tid >> 3)) * K_LCP + (tid & 7)];
  }
  __syncthreads();

  float m = -INFINITY;
  float l = 0.f;
  float acc[4] = {0.f, 0.f, 0.f, 0.f};

  for (int kt = 0; kt < T_DIM / KT; ++kt) {
    if (!tilemask[qb * 32 + kt]) {
      if (m <= NEG_VAL) {
        m = NEG_VAL;
        l += (float)KT;
        f32x4 vt = *(const f32x4*)(vtsum + (size_t)kt * C_DIM + h * HD_DIM + sub * 4);
        acc[0] += vt[0];
        acc[1] += vt[1];
        acc[2] += vt[2];
        acc[3] += vt[3];
      }
      continue;
    }
    const int k0 = kt * KT;
    __syncthreads();
#pragma unroll
    for (int it = 0; it < 4; ++it) {
      int i = tid + it * 256;
      int row = i >> 4, c4 = (i & 15) * 4;
      bf16x4 kv = *(const bf16x4*)(k + (size_t)(k0 + row) * C_DIM + h * HD_DIM + c4);
      bf16x4 vv = *(const bf16x4*)(v + (size_t)(k0 + row) * C_DIM + h * HD_DIM + c4);
      ks[row][c4 + 0] = (float)kv[0];
      ks[row][c4 + 1] = (float)kv[1];
      ks[row][c4 + 2] = (float)kv[2];
      ks[row][c4 + 3] = (float)kv[3];
      vs[row][c4 + 0] = (float)vv[0];
      vs[row][c4 + 1] = (float)vv[1];
      vs[row][c4 + 2] = (float)vv[2];
      vs[row][c4 + 3] = (float)vv[3];
    }
#pragma unroll
    for (int it = 0; it < 2; ++it) {
      int i = tid + it * 256;
      kds[i >> 3][i & 7] = kd[(size_t)(k0 + (i >> 3)) * K_LCP + (i & 7)];
    }
    __syncthreads();

    const int kb = sub * 4;
    bool msk[4];
#pragma unroll
    for (int j = 0; j < 4; ++j) {
      int kg = k0 + kb + j;
      int lcp = 0;
#pragma unroll
      for (int jj = 0; jj < K_LCP; ++jj) {
        if (qds[q_l][jj] == kds[kb + j][jj]) lcp++;
        else break;
      }
      msk[j] = (lcp >= K_LCP - 1) && (kg <= q0 + q_l);
    }
    float s[4] = {0.f, 0.f, 0.f, 0.f};
#pragma unroll
    for (int d4 = 0; d4 < 16; ++d4) {
      float4 q4 = *(const float4*)&qs[q_l][d4 * 4];
#pragma unroll
      for (int j = 0; j < 4; ++j) {
        float4 k4 = *(const float4*)&ks[kb + j][d4 * 4];
        s[j] = fmaf(q4.x, k4.x, s[j]);
        s[j] = fmaf(q4.y, k4.y, s[j]);
        s[j] = fmaf(q4.z, k4.z, s[j]);
        s[j] = fmaf(q4.w, k4.w, s[j]);
      }
    }
    float tmax = NEG_VAL;
#pragma unroll
    for (int j = 0; j < 4; ++j) {
      s[j] = msk[j] ? s[j] : NEG_VAL;
      tmax = fmaxf(tmax, s[j]);
    }
#pragma unroll
    for (int off = 1; off < 16; off <<= 1) tmax = fmaxf(tmax, __shfl_xor(tmax, off));
    float m_new = fmaxf(m, tmax);
    float alpha = expf(m - m_new);
    float lsum = 0.f;
#pragma unroll
    for (int j = 0; j < 4; ++j) {
      float p = expf(s[j] - m_new);
      sc[q_l][kb + j] = p;
      lsum += p;
    }
#pragma unroll
    for (int off = 1; off < 16; off <<= 1) lsum += __shfl_xor(lsum, off);
    l = l * alpha + lsum;
    m = m_new;
    acc[0] *= alpha;
    acc[1] *= alpha;
    acc[2] *= alpha;
    acc[3] *= alpha;
    __syncthreads();
#pragma unroll 8
    for (int kk = 0; kk < KT; ++kk) {
      float w = sc[q_l][kk];
      const float4 v4 = *(const float4*)&vs[kk][sub * 4];
      acc[0] = fmaf(w, v4.x, acc[0]);
      acc[1] = fmaf(w, v4.y, acc[1]);
      acc[2] = fmaf(w, v4.z, acc[2]);
      acc[3] = fmaf(w, v4.w, acc[3]);
    }
  }

  const float inv_l = 1.0f / l;
  bf16x4 o = {(bf16)(acc[0] * inv_l), (bf16)(acc[1] * inv_l),
              (bf16)(acc[2] * inv_l), (bf16)(acc[3] * inv_l)};
  *(bf16x4*)(y + (size_t)(q0 + q_l) * C_DIM + h * HD_DIM + sub * 4) = o;
}

extern "C" void kernel_launch(void* const* d_in, const int* in_sizes, int n_in,
                              void* d_out, int out_size, void* d_ws, size_t ws_size,
                              hipStream_t stream) {
  const float* x = (const float*)d_in[0];
  const float* cosT = (const float*)d_in[1];
  const float* sinT = (const float*)d_in[2];
  const float* Wq = (const float*)d_in[3];
  const float* Wk = (const float*)d_in[4];
  const float* Wv = (const float*)d_in[5];
  const float* Wproj = (const float*)d_in[6];
  const float* Wdq = (const float*)d_in[7];
  const float* Wdk = (const float*)d_in[8];
  float* out = (float*)d_out;

  char* ws = (char*)d_ws;
  const size_t TC2 = (size_t)T_DIM * C_DIM * 2;
  const size_t CC2 = (size_t)C_DIM * C_DIM * 2;
  bf16* xb = (bf16*)(ws + 0);
  bf16* wqt = (bf16*)(ws + TC2);
  bf16* wkt = (bf16*)(ws + TC2 + CC2);
  bf16* wvt = (bf16*)(ws + TC2 + 2 * CC2);
  bf16* wpt = (bf16*)(ws + TC2 + 3 * CC2);
  bf16* qb = (bf16*)(ws + TC2 + 4 * CC2);
  bf16* kb = (bf16*)(ws + 2 * TC2 + 4 * CC2);
  bf16* vb = (bf16*)(ws + 3 * TC2 + 4 * CC2);
  char* p2 = ws + 4 * TC2 + 4 * CC2;
  float* qd = (float*)p2;
  float* kd = (float*)(p2 + (size_t)T_DIM * K_LCP * 4);
  float* vtsum = (float*)(p2 + 2 * (size_t)T_DIM * K_LCP * 4);
  float* vmean = (float*)(p2 + 2 * (size_t)T_DIM * K_LCP * 4 + 32 * C_DIM * 4);
  int* tilemask = (int*)(p2 + 2 * (size_t)T_DIM * K_LCP * 4 + 33 * C_DIM * 4);
  int* allmask = tilemask + (T_DIM / QT) * 32;
  int* qneed = allmask + (T_DIM / QT);
  int* kneed = qneed + 16;
  bf16* yb = xb;  // x (bf16) is dead after the QKV GEMM

  convert_qdkd<<<T_DIM / 4, 256, 0, stream>>>(x, Wdq, Wdk, xb, qd, kd);
  transpose_w<<<dim3(16, 16, 4), 256, 0, stream>>>(Wq, Wk, Wv, Wproj, wqt, wkt,
                                                   wvt, wpt);
  tilemask_kernel<<<T_DIM / QT, 256, 0, stream>>>(qd, kd, tilemask, allmask);
  need_kernel<<<1, 256, 0, stream>>>(tilemask, allmask, qneed, kneed);
  gemm_bf16<128, 4, 2><<<dim3(C_DIM / 128, T_DIM / 128, 3), 256, 0, stream>>>(
      xb, wqt, wkt, wvt, qb, kb, vb, C_DIM, C_DIM, 1, cosT, sinT, qneed, kneed, 1);
  vtsum_kernel<<<dim3(T_DIM / KT, 4), 256, 0, stream>>>(vb, vtsum);
  vmean_kernel<<<4, 256, 0, stream>>>(vtsum, vmean);
  attn2<<<dim3(T_DIM / QT, H_NUM), 256, 0, stream>>>(
      qb, kb, vb, qd, kd, vtsum, vmean, tilemask, allmask, yb);
  gemm_bf16<64, 2, 1><<<dim3(C_DIM / 128, T_DIM / 64, 1), 256, 0, stream>>>(
      yb, wpt, wpt, wpt, out, out, out, C_DIM, C_DIM, 0, cosT, sinT, qneed, kneed, 0);
}

// Round 5
// 157.678 us; speedup vs baseline: 3.7906x; 1.0804x over previous
//
#include <hip/hip_runtime.h>
#include <math.h>

#define T_DIM 2048
#define C_DIM 1024
#define H_NUM 16
#define HD_DIM 64
#define K_LCP 8
#define NEG_VAL -1.0e9f

typedef __bf16 bf16;
typedef __bf16 bf16x4 __attribute__((ext_vector_type(4)));
typedef __bf16 bf16x8 __attribute__((ext_vector_type(8)));
typedef float f32x4 __attribute__((ext_vector_type(4)));

// ------- convert x fp32->bf16 AND qd=x@Wdq, kd=x@Wdk (one wave per row) ---------
__global__ __launch_bounds__(256) void convert_qdkd(const float* __restrict__ x,
                                                    const float* __restrict__ Wdq,
                                                    const float* __restrict__ Wdk,
                                                    bf16* __restrict__ xb,
                                                    float* __restrict__ qd,
                                                    float* __restrict__ kd) {
  const int wave = threadIdx.x >> 6, lane = threadIdx.x & 63;
  const int t = blockIdx.x * 4 + wave;
  const float* xp = x + (size_t)t * C_DIM;
  bf16* xbp = xb + (size_t)t * C_DIM;
  float aq[8] = {}, ak[8] = {};
#pragma unroll
  for (int i = 0; i < 16; ++i) {
    const int c = i * 64 + lane;
    float xv = xp[c];
    xbp[c] = (bf16)xv;
    float4 wq0 = *(const float4*)(Wdq + (size_t)c * K_LCP);
    float4 wq1 = *(const float4*)(Wdq + (size_t)c * K_LCP + 4);
    float4 wk0 = *(const float4*)(Wdk + (size_t)c * K_LCP);
    float4 wk1 = *(const float4*)(Wdk + (size_t)c * K_LCP + 4);
    aq[0] = fmaf(xv, wq0.x, aq[0]); aq[1] = fmaf(xv, wq0.y, aq[1]);
    aq[2] = fmaf(xv, wq0.z, aq[2]); aq[3] = fmaf(xv, wq0.w, aq[3]);
    aq[4] = fmaf(xv, wq1.x, aq[4]); aq[5] = fmaf(xv, wq1.y, aq[5]);
    aq[6] = fmaf(xv, wq1.z, aq[6]); aq[7] = fmaf(xv, wq1.w, aq[7]);
    ak[0] = fmaf(xv, wk0.x, ak[0]); ak[1] = fmaf(xv, wk0.y, ak[1]);
    ak[2] = fmaf(xv, wk0.z, ak[2]); ak[3] = fmaf(xv, wk0.w, ak[3]);
    ak[4] = fmaf(xv, wk1.x, ak[4]); ak[5] = fmaf(xv, wk1.y, ak[5]);
    ak[6] = fmaf(xv, wk1.z, ak[6]); ak[7] = fmaf(xv, wk1.w, ak[7]);
  }
#pragma unroll
  for (int j = 0; j < 8; ++j) {
#pragma unroll
    for (int off = 32; off >= 1; off >>= 1) {
      aq[j] += __shfl_xor(aq[j], off);
      ak[j] += __shfl_xor(ak[j], off);
    }
  }
  if (lane == 0) {
    *(float4*)(qd + (size_t)t * K_LCP) = make_float4(aq[0], aq[1], aq[2], aq[3]);
    *(float4*)(qd + (size_t)t * K_LCP + 4) = make_float4(aq[4], aq[5], aq[6], aq[7]);
    *(float4*)(kd + (size_t)t * K_LCP) = make_float4(ak[0], ak[1], ak[2], ak[3]);
    *(float4*)(kd + (size_t)t * K_LCP + 4) = make_float4(ak[4], ak[5], ak[6], ak[7]);
  }
}

// ---------------- xpartial[b][c] = sum of x rows [64b,64b+64) -------------------
__global__ __launch_bounds__(256) void xpartial_kernel(const float* __restrict__ x,
                                                       float* __restrict__ partial) {
  const int b = blockIdx.x;
  const int t = threadIdx.x;
  f32x4 s = {0.f, 0.f, 0.f, 0.f};
  for (int r = 0; r < 64; ++r)
    s += ((const f32x4*)(x + (size_t)(b * 64 + r) * C_DIM))[t];
  ((f32x4*)(partial + (size_t)b * C_DIM))[t] = s;
}

// ------- matvec: vout[j] = scale * sum_c vin[c] * W[c][j] -----------------------
// npart>0: vin is [npart][1024] partials to reduce first.
__global__ __launch_bounds__(256) void matvec_kernel(const float* __restrict__ vin,
                                                     int npart,
                                                     const float* __restrict__ W,
                                                     float* __restrict__ vout,
                                                     float scale) {
  __shared__ float xm[C_DIM];
  __shared__ float red[4][64];
  const int t = threadIdx.x;
  f32x4 s = {0.f, 0.f, 0.f, 0.f};
  if (npart) {
    for (int g = 0; g < npart; ++g) s += ((const f32x4*)vin)[g * 256 + t];
  } else {
    s = ((const f32x4*)vin)[t];
  }
  s *= scale;
  *(f32x4*)&xm[t * 4] = s;
  __syncthreads();
  const int j = blockIdx.x * 64 + (t & 63);
  const int p = t >> 6;
  float acc = 0.f;
  for (int c = p * 256; c < p * 256 + 256; ++c)
    acc = fmaf(xm[c], W[(size_t)c * C_DIM + j], acc);
  red[p][t & 63] = acc;
  __syncthreads();
  if (t < 64)
    vout[blockIdx.x * 64 + t] = (red[0][t] + red[1][t]) + (red[2][t] + red[3][t]);
}

// ---------------- transpose + convert weights (flagged) -------------------------
__global__ __launch_bounds__(256) void transpose_w(const float* __restrict__ W0,
                                                   const float* __restrict__ W1,
                                                   const float* __restrict__ W2,
                                                   const float* __restrict__ W3,
                                                   bf16* __restrict__ O0,
                                                   bf16* __restrict__ O1,
                                                   bf16* __restrict__ O2,
                                                   bf16* __restrict__ O3,
                                                   const int* __restrict__ wneed) {
  if (!wneed[blockIdx.z]) return;
  const float* W = (blockIdx.z == 0) ? W0 : (blockIdx.z == 1) ? W1
                   : (blockIdx.z == 2) ? W2 : W3;
  bf16* O = (blockIdx.z == 0) ? O0 : (blockIdx.z == 1) ? O1
            : (blockIdx.z == 2) ? O2 : O3;
  __shared__ bf16 tile[64][65];
  const int bk = blockIdx.y * 64;
  const int bn = blockIdx.x * 64;
  const int r = threadIdx.x >> 2;
  const int c0 = (threadIdx.x & 3) * 16;
  const float* src = W + (size_t)(bk + r) * C_DIM + bn + c0;
#pragma unroll
  for (int t = 0; t < 16; t += 4) {
    float4 f = *(const float4*)(src + t);
    tile[r][c0 + t + 0] = (bf16)f.x;
    tile[r][c0 + t + 1] = (bf16)f.y;
    tile[r][c0 + t + 2] = (bf16)f.z;
    tile[r][c0 + t + 3] = (bf16)f.w;
  }
  __syncthreads();
  bf16* dst = O + (size_t)(bn + r) * C_DIM + bk + c0;
#pragma unroll
  for (int t = 0; t < 16; ++t) dst[t] = tile[c0 + t][r];
}

// -------- tilemask[qb][kt] + allmask[qb] ----------------------------------------
__global__ __launch_bounds__(256) void tilemask_kernel(const float* __restrict__ qd,
                                                       const float* __restrict__ kd,
                                                       int* __restrict__ tilemask,
                                                       int* __restrict__ allmask) {
  const int qb = blockIdx.x;
  __shared__ float qds[16][K_LCP];
  __shared__ int tm[32];
  const int tid = threadIdx.x;
  if (tid < 32) tm[tid] = 0;
  if (tid < 16 * K_LCP)
    qds[tid >> 3][tid & 7] = qd[(size_t)(qb * 16 + (tid >> 3)) * K_LCP + (tid & 7)];
  __syncthreads();
  for (int key = tid; key < T_DIM; key += 256) {
    float kv[K_LCP];
    *(float4*)&kv[0] = *(const float4*)(kd + (size_t)key * K_LCP);
    *(float4*)&kv[4] = *(const float4*)(kd + (size_t)key * K_LCP + 4);
    int any = 0;
#pragma unroll
    for (int ql = 0; ql < 16; ++ql) {
      int qg = qb * 16 + ql;
      if (key > qg) continue;
      int lcp = 0;
#pragma unroll
      for (int jj = 0; jj < K_LCP; ++jj) {
        if (qds[ql][jj] == kv[jj]) lcp++;
        else break;
      }
      if (lcp >= K_LCP - 1) any = 1;
    }
    if (any) tm[key >> 6] = 1;  // benign race: same value
  }
  __syncthreads();
  if (tid < 32) tilemask[qb * 32 + tid] = tm[tid];
  if (tid == 0) {
    int any = 0;
#pragma unroll
    for (int i = 0; i < 32; ++i) any |= tm[i];
    allmask[qb] = !any;
  }
}

// -------- need flags ------------------------------------------------------------
__global__ __launch_bounds__(256) void need_kernel(
    const int* __restrict__ tilemask, const int* __restrict__ allmask,
    int* __restrict__ qneed, int* __restrict__ kneed, int* __restrict__ vneed,
    int* __restrict__ vtneed, int* __restrict__ pneed, int* __restrict__ wneed) {
  __shared__ int tmor[32], vt[32], am[128], qn[16], kn[16], vn[16], pn[32];
  const int tid = threadIdx.x;
  if (tid < 128) am[tid] = allmask[tid];
  __syncthreads();
  if (tid < 32) {
    int o = 0, v = 0;
    for (int qb = 0; qb < T_DIM / 16; ++qb) {
      int tm = tilemask[qb * 32 + tid];
      o |= tm;
      v |= ((!am[qb]) && (!tm));
    }
    tmor[tid] = o;
    vt[tid] = v;
    vtneed[tid] = v;
  }
  __syncthreads();
  if (tid < 16) {
    int kn_ = tmor[2 * tid] | tmor[2 * tid + 1];
    kn[tid] = kn_;
    kneed[tid] = kn_;
    int q = 0;
#pragma unroll
    for (int j = 0; j < 8; ++j) q |= !am[tid * 8 + j];
    qn[tid] = q;
    qneed[tid] = q;
    int v_ = kn_ | vt[2 * tid] | vt[2 * tid + 1];
    vn[tid] = v_;
    vneed[tid] = v_;
  }
  if (tid >= 32 && tid < 64) {
    int i = tid - 32, p = 0;
#pragma unroll
    for (int j = 0; j < 4; ++j) p |= !am[i * 4 + j];
    pn[i] = p;
    pneed[i] = p;
  }
  __syncthreads();
  if (tid == 0) {
    int a = 0, b = 0, c = 0, d = 0;
    for (int i = 0; i < 16; ++i) { a |= qn[i]; b |= kn[i]; c |= vn[i]; }
    for (int i = 0; i < 32; ++i) d |= pn[i];
    wneed[0] = a; wneed[1] = b; wneed[2] = c; wneed[3] = d;
  }
}

// ------- bf16 MFMA GEMM (m97 structure) w/ fused RoPE+RMS epilogue & skip -------
// mode=1: QKV (z selects q/k/v, flags fq/fk/fv, rope for z<2); mode=0: proj (fq).
template <int TMt, int MI, int NA>
__global__ __launch_bounds__(256) void gemm_bf16(
    const bf16* __restrict__ A, const bf16* __restrict__ Bt0,
    const bf16* __restrict__ Bt1, const bf16* __restrict__ Bt2, void* C0,
    void* C1, void* C2, int N, int Kd, int bf16_out,
    const float* __restrict__ cosT, const float* __restrict__ sinT,
    const int* __restrict__ fq, const int* __restrict__ fk,
    const int* __restrict__ fv, int mode) {
  if (mode) {
    const int* f = (blockIdx.z == 0) ? fq : (blockIdx.z == 1) ? fk : fv;
    if (!f[blockIdx.y]) return;
  } else {
    if (!fq[blockIdx.y]) return;
  }
  const bf16* Bt = (blockIdx.z == 0) ? Bt0 : (blockIdx.z == 1) ? Bt1 : Bt2;
  __shared__ __align__(16) bf16 As[TMt * 32];
  __shared__ __align__(16) bf16 Bs[128 * 32];
  const int tid = threadIdx.x;
  const int bm = blockIdx.y * TMt;
  const int bn = blockIdx.x * 128;
  const int wave = tid >> 6, lane = tid & 63;
  const int lr = lane >> 2;
  const int lc = (lane & 3) * 8;
  bf16* gA = (bf16*)(A + (size_t)(bm + wave * 16 * NA + lr) * Kd + lc);
  bf16* gB = (bf16*)(Bt + (size_t)(bn + wave * 32 + lr) * Kd + lc);
  bf16* lA = As + wave * 512 * NA;
  bf16* lB = Bs + wave * 1024;
  const int wr = (wave >> 1) * (MI * 16);
  const int wc = (wave & 1) * 64;
  const int fm = lane & 15;
  const int fk_ = (lane >> 4) * 8;

  f32x4 acc[MI][4] = {};
  for (int k0 = 0; k0 < Kd; k0 += 32) {
    __syncthreads();
#pragma unroll
    for (int u = 0; u < NA; ++u)
      __builtin_amdgcn_global_load_lds(
          (__attribute__((address_space(1))) void*)(gA + (size_t)u * 16 * Kd + k0),
          (__attribute__((address_space(3))) void*)(lA + u * 512), 16, 0, 0);
#pragma unroll
    for (int u = 0; u < 2; ++u)
      __builtin_amdgcn_global_load_lds(
          (__attribute__((address_space(1))) void*)(gB + (size_t)u * 16 * Kd + k0),
          (__attribute__((address_space(3))) void*)(lB + u * 512), 16, 0, 0);
    __syncthreads();
    bf16x8 af[MI], bfr[4];
#pragma unroll
    for (int i = 0; i < MI; ++i)
      af[i] = *(const bf16x8*)(As + (size_t)(wr + i * 16 + fm) * 32 + fk_);
#pragma unroll
    for (int j = 0; j < 4; ++j)
      bfr[j] = *(const bf16x8*)(Bs + (size_t)(wc + j * 16 + fm) * 32 + fk_);
#pragma unroll
    for (int i = 0; i < MI; ++i)
#pragma unroll
      for (int j = 0; j < 4; ++j)
        acc[i][j] = __builtin_amdgcn_mfma_f32_16x16x32_bf16(af[i], bfr[j],
                                                            acc[i][j], 0, 0, 0);
  }
  const int cq = (lane >> 4) * 4;
  if (mode && blockIdx.z < 2) {
    bf16* C = (bf16*)((blockIdx.z == 0) ? C0 : C1);
#pragma unroll
    for (int i = 0; i < MI; ++i)
#pragma unroll
      for (int r = 0; r < 4; ++r) {
        const int t = bm + wr + i * 16 + cq + r;
        float c0 = cosT[(size_t)t * 32 + fm], s0 = sinT[(size_t)t * 32 + fm];
        float c1 = cosT[(size_t)t * 32 + 16 + fm], s1 = sinT[(size_t)t * 32 + 16 + fm];
        float a0 = acc[i][0][r], a1 = acc[i][1][r];
        float a2 = acc[i][2][r], a3 = acc[i][3][r];
        float o0 = a0 * c0 - a2 * s0, o2 = a0 * s0 + a2 * c0;
        float o1 = a1 * c1 - a3 * s1, o3 = a1 * s1 + a3 * c1;
        float ss = o0 * o0 + o1 * o1 + o2 * o2 + o3 * o3;
        ss += __shfl_xor(ss, 1);
        ss += __shfl_xor(ss, 2);
        ss += __shfl_xor(ss, 4);
        ss += __shfl_xor(ss, 8);
        float rn = 1.0f / sqrtf(ss * (1.0f / 64.0f) + 1e-6f);
        size_t base = (size_t)t * N + bn + wc + fm;
        C[base + 0] = (bf16)(o0 * rn);
        C[base + 16] = (bf16)(o1 * rn);
        C[base + 32] = (bf16)(o2 * rn);
        C[base + 48] = (bf16)(o3 * rn);
      }
  } else if (bf16_out) {
    bf16* C = (bf16*)((blockIdx.z == 0) ? C0 : (blockIdx.z == 1) ? C1 : C2);
#pragma unroll
    for (int i = 0; i < MI; ++i)
#pragma unroll
      for (int r = 0; r < 4; ++r) {
        size_t base = (size_t)(bm + wr + i * 16 + cq + r) * N + bn + wc + fm;
#pragma unroll
        for (int j = 0; j < 4; ++j) C[base + j * 16] = (bf16)acc[i][j][r];
      }
  } else {
    float* C = (float*)((blockIdx.z == 0) ? C0 : (blockIdx.z == 1) ? C1 : C2);
#pragma unroll
    for (int i = 0; i < MI; ++i)
#pragma unroll
      for (int r = 0; r < 4; ++r) {
        size_t base = (size_t)(bm + wr + i * 16 + cq + r) * N + bn + wc + fm;
#pragma unroll
        for (int j = 0; j < 4; ++j) C[base + j * 16] = acc[i][j][r];
      }
  }
}

// ---------------- vtsum[kt][c] (flagged) ----------------------------------------
__global__ __launch_bounds__(256) void vtsum_kernel(const bf16* __restrict__ v,
                                                    float* __restrict__ vtsum,
                                                    const int* __restrict__ vtneed) {
  const int kt = blockIdx.x;
  if (!vtneed[kt]) return;
  const int col = blockIdx.y * 256 + threadIdx.x;
  float s = 0.f;
#pragma unroll 8
  for (int r = 0; r < 64; ++r) s += (float)v[(size_t)(kt * 64 + r) * C_DIM + col];
  vtsum[(size_t)kt * C_DIM + col] = s;
}

// ---------------- flash attention w/ tile mask, V sums, all-masked exit ---------
#define QT 16
#define KT 64

__global__ __launch_bounds__(256) void attn2(
    const bf16* __restrict__ q, const bf16* __restrict__ k,
    const bf16* __restrict__ v, const float* __restrict__ qd,
    const float* __restrict__ kd, const float* __restrict__ vtsum,
    const float* __restrict__ vmean, const int* __restrict__ tilemask,
    const int* __restrict__ allmask, bf16* __restrict__ y) {
  const int h = blockIdx.y;
  const int qb = blockIdx.x;
  const int q0 = qb * QT;
  const int tid = threadIdx.x;
  const int q_l = tid >> 4;
  const int sub = tid & 15;

  if (allmask[qb]) {
    f32x4 vm = *(const f32x4*)(vmean + h * HD_DIM + sub * 4);
    bf16x4 o = {(bf16)vm[0], (bf16)vm[1], (bf16)vm[2], (bf16)vm[3]};
    *(bf16x4*)(y + (size_t)(q0 + q_l) * C_DIM + h * HD_DIM + sub * 4) = o;
    return;
  }

  __shared__ float qs[QT][HD_DIM];
  __shared__ float qds[QT][K_LCP];
  __shared__ float ks[KT][HD_DIM];
  __shared__ float vs[KT][HD_DIM];
  __shared__ float kds[KT][K_LCP];
  __shared__ float sc[QT][KT + 4];

  {
    int r = tid >> 4, c4 = (tid & 15) * 4;
    bf16x4 t4 = *(const bf16x4*)(q + (size_t)(q0 + r) * C_DIM + h * HD_DIM + c4);
    qs[r][c4 + 0] = (float)t4[0] * 0.125f;
    qs[r][c4 + 1] = (float)t4[1] * 0.125f;
    qs[r][c4 + 2] = (float)t4[2] * 0.125f;
    qs[r][c4 + 3] = (float)t4[3] * 0.125f;
    if (tid < QT * K_LCP)
      qds[tid >> 3][tid & 7] = qd[(size_t)(q0 + (tid >> 3)) * K_LCP + (tid & 7)];
  }
  __syncthreads();

  float m = -INFINITY;
  float l = 0.f;
  float acc[4] = {0.f, 0.f, 0.f, 0.f};

  for (int kt = 0; kt < T_DIM / KT; ++kt) {
    if (!tilemask[qb * 32 + kt]) {
      if (m <= NEG_VAL) {
        m = NEG_VAL;
        l += (float)KT;
        f32x4 vt = *(const f32x4*)(vtsum + (size_t)kt * C_DIM + h * HD_DIM + sub * 4);
        acc[0] += vt[0];
        acc[1] += vt[1];
        acc[2] += vt[2];
        acc[3] += vt[3];
      }
      continue;
    }
    const int k0 = kt * KT;
    __syncthreads();
#pragma unroll
    for (int it = 0; it < 4; ++it) {
      int i = tid + it * 256;
      int row = i >> 4, c4 = (i & 15) * 4;
      bf16x4 kv = *(const bf16x4*)(k + (size_t)(k0 + row) * C_DIM + h * HD_DIM + c4);
      bf16x4 vv = *(const bf16x4*)(v + (size_t)(k0 + row) * C_DIM + h * HD_DIM + c4);
      ks[row][c4 + 0] = (float)kv[0];
      ks[row][c4 + 1] = (float)kv[1];
      ks[row][c4 + 2] = (float)kv[2];
      ks[row][c4 + 3] = (float)kv[3];
      vs[row][c4 + 0] = (float)vv[0];
      vs[row][c4 + 1] = (float)vv[1];
      vs[row][c4 + 2] = (float)vv[2];
      vs[row][c4 + 3] = (float)vv[3];
    }
#pragma unroll
    for (int it = 0; it < 2; ++it) {
      int i = tid + it * 256;
      kds[i >> 3][i & 7] = kd[(size_t)(k0 + (i >> 3)) * K_LCP + (i & 7)];
    }
    __syncthreads();

    const int kb = sub * 4;
    bool msk[4];
#pragma unroll
    for (int j = 0; j < 4; ++j) {
      int kg = k0 + kb + j;
      int lcp = 0;
#pragma unroll
      for (int jj = 0; jj < K_LCP; ++jj) {
        if (qds[q_l][jj] == kds[kb + j][jj]) lcp++;
        else break;
      }
      msk[j] = (lcp >= K_LCP - 1) && (kg <= q0 + q_l);
    }
    float s[4] = {0.f, 0.f, 0.f, 0.f};
#pragma unroll
    for (int d4 = 0; d4 < 16; ++d4) {
      float4 q4 = *(const float4*)&qs[q_l][d4 * 4];
#pragma unroll
      for (int j = 0; j < 4; ++j) {
        float4 k4 = *(const float4*)&ks[kb + j][d4 * 4];
        s[j] = fmaf(q4.x, k4.x, s[j]);
        s[j] = fmaf(q4.y, k4.y, s[j]);
        s[j] = fmaf(q4.z, k4.z, s[j]);
        s[j] = fmaf(q4.w, k4.w, s[j]);
      }
    }
    float tmax = NEG_VAL;
#pragma unroll
    for (int j = 0; j < 4; ++j) {
      s[j] = msk[j] ? s[j] : NEG_VAL;
      tmax = fmaxf(tmax, s[j]);
    }
#pragma unroll
    for (int off = 1; off < 16; off <<= 1) tmax = fmaxf(tmax, __shfl_xor(tmax, off));
    float m_new = fmaxf(m, tmax);
    float alpha = expf(m - m_new);
    float lsum = 0.f;
#pragma unroll
    for (int j = 0; j < 4; ++j) {
      float p = expf(s[j] - m_new);
      sc[q_l][kb + j] = p;
      lsum += p;
    }
#pragma unroll
    for (int off = 1; off < 16; off <<= 1) lsum += __shfl_xor(lsum, off);
    l = l * alpha + lsum;
    m = m_new;
    acc[0] *= alpha;
    acc[1] *= alpha;
    acc[2] *= alpha;
    acc[3] *= alpha;
    __syncthreads();
#pragma unroll 8
    for (int kk = 0; kk < KT; ++kk) {
      float w = sc[q_l][kk];
      const float4 v4 = *(const float4*)&vs[kk][sub * 4];
      acc[0] = fmaf(w, v4.x, acc[0]);
      acc[1] = fmaf(w, v4.y, acc[1]);
      acc[2] = fmaf(w, v4.z, acc[2]);
      acc[3] = fmaf(w, v4.w, acc[3]);
    }
  }

  const float inv_l = 1.0f / l;
  bf16x4 o = {(bf16)(acc[0] * inv_l), (bf16)(acc[1] * inv_l),
              (bf16)(acc[2] * inv_l), (bf16)(acc[3] * inv_l)};
  *(bf16x4*)(y + (size_t)(q0 + q_l) * C_DIM + h * HD_DIM + sub * 4) = o;
}

// -------- broadcast rowout into fully-all-masked 64-row out blocks --------------
__global__ __launch_bounds__(256) void bcast_out(const float* __restrict__ rowout,
                                                 const int* __restrict__ pneed,
                                                 float* __restrict__ out) {
  f32x4 v = ((const f32x4*)rowout)[threadIdx.x];
  const int r0 = blockIdx.x * 8;
#pragma unroll
  for (int r = 0; r < 8; ++r) {
    const int row = r0 + r;
    if (pneed[row >> 6]) continue;
    ((f32x4*)(out + (size_t)row * C_DIM))[threadIdx.x] = v;
  }
}

extern "C" void kernel_launch(void* const* d_in, const int* in_sizes, int n_in,
                              void* d_out, int out_size, void* d_ws, size_t ws_size,
                              hipStream_t stream) {
  const float* x = (const float*)d_in[0];
  const float* cosT = (const float*)d_in[1];
  const float* sinT = (const float*)d_in[2];
  const float* Wq = (const float*)d_in[3];
  const float* Wk = (const float*)d_in[4];
  const float* Wv = (const float*)d_in[5];
  const float* Wproj = (const float*)d_in[6];
  const float* Wdq = (const float*)d_in[7];
  const float* Wdk = (const float*)d_in[8];
  float* out = (float*)d_out;

  char* ws = (char*)d_ws;
  const size_t TC2 = (size_t)T_DIM * C_DIM * 2;
  const size_t CC2 = (size_t)C_DIM * C_DIM * 2;
  bf16* xb = (bf16*)(ws + 0);
  bf16* wqt = (bf16*)(ws + TC2);
  bf16* wkt = (bf16*)(ws + TC2 + CC2);
  bf16* wvt = (bf16*)(ws + TC2 + 2 * CC2);
  bf16* wpt = (bf16*)(ws + TC2 + 3 * CC2);
  bf16* qb = (bf16*)(ws + TC2 + 4 * CC2);
  bf16* kb = (bf16*)(ws + 2 * TC2 + 4 * CC2);
  bf16* vb = (bf16*)(ws + 3 * TC2 + 4 * CC2);
  char* p2 = ws + 4 * TC2 + 4 * CC2;
  float* qd = (float*)p2;                      p2 += (size_t)T_DIM * K_LCP * 4;
  float* kd = (float*)p2;                      p2 += (size_t)T_DIM * K_LCP * 4;
  float* vtsum = (float*)p2;                   p2 += 32 * C_DIM * 4;
  float* vmean = (float*)p2;                   p2 += C_DIM * 4;
  float* partial = (float*)p2;                 p2 += 32 * C_DIM * 4;
  float* rowout = (float*)p2;                  p2 += C_DIM * 4;
  int* tilemask = (int*)p2;                    p2 += (T_DIM / 16) * 32 * 4;
  int* allmask = (int*)p2;                     p2 += (T_DIM / 16) * 4;
  int* qneed = (int*)p2;                       p2 += 16 * 4;
  int* kneed = (int*)p2;                       p2 += 16 * 4;
  int* vneed = (int*)p2;                       p2 += 16 * 4;
  int* vtneed = (int*)p2;                      p2 += 32 * 4;
  int* pneed = (int*)p2;                       p2 += 32 * 4;
  int* wneed = (int*)p2;                       p2 += 4 * 4;
  bf16* yb = xb;  // x (bf16) is dead after the QKV GEMM

  convert_qdkd<<<T_DIM / 4, 256, 0, stream>>>(x, Wdq, Wdk, xb, qd, kd);
  xpartial_kernel<<<32, 256, 0, stream>>>(x, partial);
  tilemask_kernel<<<T_DIM / QT, 256, 0, stream>>>(qd, kd, tilemask, allmask);
  need_kernel<<<1, 256, 0, stream>>>(tilemask, allmask, qneed, kneed, vneed,
                                     vtneed, pneed, wneed);
  matvec_kernel<<<16, 256, 0, stream>>>(partial, 32, Wv, vmean, 1.0f / 2048.0f);
  matvec_kernel<<<16, 256, 0, stream>>>(vmean, 0, Wproj, rowout, 1.0f);
  transpose_w<<<dim3(16, 16, 4), 256, 0, stream>>>(Wq, Wk, Wv, Wproj, wqt, wkt,
                                                   wvt, wpt, wneed);
  gemm_bf16<128, 4, 2><<<dim3(C_DIM / 128, T_DIM / 128, 3), 256, 0, stream>>>(
      xb, wqt, wkt, wvt, qb, kb, vb, C_DIM, C_DIM, 1, cosT, sinT, qneed, kneed,
      vneed, 1);
  vtsum_kernel<<<dim3(T_DIM / KT, 4), 256, 0, stream>>>(vb, vtsum, vtneed);
  attn2<<<dim3(T_DIM / QT, H_NUM), 256, 0, stream>>>(
      qb, kb, vb, qd, kd, vtsum, vmean, tilemask, allmask, yb);
  gemm_bf16<64, 2, 1><<<dim3(C_DIM / 128, T_DIM / 64, 1), 256, 0, stream>>>(
      yb, wpt, wpt, wpt, out, out, out, C_DIM, C_DIM, 0, cosT, sinT, pneed,
      pneed, pneed, 0);
  bcast_out<<<T_DIM / 8, 256, 0, stream>>>(rowout, pneed, out);
}

// Round 6
// 147.835 us; speedup vs baseline: 4.0430x; 1.0666x over previous
//
#include <hip/hip_runtime.h>
#include <math.h>

#define T_DIM 2048
#define C_DIM 1024
#define H_NUM 16
#define HD_DIM 64
#define K_LCP 8
#define NEG_VAL -1.0e9f

typedef __bf16 bf16;
typedef __bf16 bf16x4 __attribute__((ext_vector_type(4)));
typedef __bf16 bf16x8 __attribute__((ext_vector_type(8)));
typedef float f32x4 __attribute__((ext_vector_type(4)));

// ------- convert x fp32->bf16 AND qd=x@Wdq, kd=x@Wdk (one wave per row) ---------
__global__ __launch_bounds__(256) void convert_qdkd(const float* __restrict__ x,
                                                    const float* __restrict__ Wdq,
                                                    const float* __restrict__ Wdk,
                                                    bf16* __restrict__ xb,
                                                    float* __restrict__ qd,
                                                    float* __restrict__ kd) {
  const int wave = threadIdx.x >> 6, lane = threadIdx.x & 63;
  const int t = blockIdx.x * 4 + wave;
  const float* xp = x + (size_t)t * C_DIM;
  bf16* xbp = xb + (size_t)t * C_DIM;
  float aq[8] = {}, ak[8] = {};
#pragma unroll
  for (int i = 0; i < 16; ++i) {
    const int c = i * 64 + lane;
    float xv = xp[c];
    xbp[c] = (bf16)xv;
    float4 wq0 = *(const float4*)(Wdq + (size_t)c * K_LCP);
    float4 wq1 = *(const float4*)(Wdq + (size_t)c * K_LCP + 4);
    float4 wk0 = *(const float4*)(Wdk + (size_t)c * K_LCP);
    float4 wk1 = *(const float4*)(Wdk + (size_t)c * K_LCP + 4);
    aq[0] = fmaf(xv, wq0.x, aq[0]); aq[1] = fmaf(xv, wq0.y, aq[1]);
    aq[2] = fmaf(xv, wq0.z, aq[2]); aq[3] = fmaf(xv, wq0.w, aq[3]);
    aq[4] = fmaf(xv, wq1.x, aq[4]); aq[5] = fmaf(xv, wq1.y, aq[5]);
    aq[6] = fmaf(xv, wq1.z, aq[6]); aq[7] = fmaf(xv, wq1.w, aq[7]);
    ak[0] = fmaf(xv, wk0.x, ak[0]); ak[1] = fmaf(xv, wk0.y, ak[1]);
    ak[2] = fmaf(xv, wk0.z, ak[2]); ak[3] = fmaf(xv, wk0.w, ak[3]);
    ak[4] = fmaf(xv, wk1.x, ak[4]); ak[5] = fmaf(xv, wk1.y, ak[5]);
    ak[6] = fmaf(xv, wk1.z, ak[6]); ak[7] = fmaf(xv, wk1.w, ak[7]);
  }
#pragma unroll
  for (int j = 0; j < 8; ++j) {
#pragma unroll
    for (int off = 32; off >= 1; off >>= 1) {
      aq[j] += __shfl_xor(aq[j], off);
      ak[j] += __shfl_xor(ak[j], off);
    }
  }
  if (lane == 0) {
    *(float4*)(qd + (size_t)t * K_LCP) = make_float4(aq[0], aq[1], aq[2], aq[3]);
    *(float4*)(qd + (size_t)t * K_LCP + 4) = make_float4(aq[4], aq[5], aq[6], aq[7]);
    *(float4*)(kd + (size_t)t * K_LCP) = make_float4(ak[0], ak[1], ak[2], ak[3]);
    *(float4*)(kd + (size_t)t * K_LCP + 4) = make_float4(ak[4], ak[5], ak[6], ak[7]);
  }
}

// -------- tilemask[qb][kt] + allmask[qb]  (blocks 0..127)  --------------------
// -------- + xpartial arm (blocks 128..159): partial[b][c]=sum x rows ----------
__global__ __launch_bounds__(256) void tilemask_fused(
    const float* __restrict__ qd, const float* __restrict__ kd,
    const float* __restrict__ x, int* __restrict__ tilemask,
    int* __restrict__ allmask, float* __restrict__ partial) {
  const int tid = threadIdx.x;
  if (blockIdx.x >= 128) {  // xpartial arm
    const int b = blockIdx.x - 128;
    f32x4 s = {0.f, 0.f, 0.f, 0.f};
    for (int r = 0; r < 64; ++r)
      s += ((const f32x4*)(x + (size_t)(b * 64 + r) * C_DIM))[tid];
    ((f32x4*)(partial + (size_t)b * C_DIM))[tid] = s;
    return;
  }
  const int qb = blockIdx.x;
  __shared__ float qds[16][K_LCP];
  __shared__ int tm[32];
  if (tid < 32) tm[tid] = 0;
  if (tid < 16 * K_LCP)
    qds[tid >> 3][tid & 7] = qd[(size_t)(qb * 16 + (tid >> 3)) * K_LCP + (tid & 7)];
  __syncthreads();
  for (int key = tid; key < T_DIM; key += 256) {
    float kv[K_LCP];
    *(float4*)&kv[0] = *(const float4*)(kd + (size_t)key * K_LCP);
    *(float4*)&kv[4] = *(const float4*)(kd + (size_t)key * K_LCP + 4);
    int any = 0;
#pragma unroll
    for (int ql = 0; ql < 16; ++ql) {
      int qg = qb * 16 + ql;
      if (key > qg) continue;
      int lcp = 0;
#pragma unroll
      for (int jj = 0; jj < K_LCP; ++jj) {
        if (qds[ql][jj] == kv[jj]) lcp++;
        else break;
      }
      if (lcp >= K_LCP - 1) any = 1;
    }
    if (any) tm[key >> 6] = 1;  // benign race: same value
  }
  __syncthreads();
  if (tid < 32) tilemask[qb * 32 + tid] = tm[tid];
  if (tid == 0) {
    int any = 0;
#pragma unroll
    for (int i = 0; i < 32; ++i) any |= tm[i];
    allmask[qb] = !any;
  }
}

// ------- matvec: vout[j] = scale * sum_c vin[c] * W[c][j] -----------------------
// npart>0: vin is [npart][1024] partials. Block 0 optionally computes need flags
// (tilemask/allmask written by the previous launch -> visible).
__global__ __launch_bounds__(256) void matvec_kernel(
    const float* __restrict__ vin, int npart, const float* __restrict__ W,
    float* __restrict__ vout, float scale, const int* __restrict__ tilemask,
    const int* __restrict__ allmask, int* __restrict__ qneed,
    int* __restrict__ kneed, int* __restrict__ vneed, int* __restrict__ vtneed,
    int* __restrict__ pneed, int* __restrict__ wneed, int do_need) {
  __shared__ float xm[C_DIM];
  __shared__ float red[4][64];
  const int t = threadIdx.x;
  f32x4 s = {0.f, 0.f, 0.f, 0.f};
  if (npart) {
    for (int g = 0; g < npart; ++g) s += ((const f32x4*)vin)[g * 256 + t];
  } else {
    s = ((const f32x4*)vin)[t];
  }
  s *= scale;
  *(f32x4*)&xm[t * 4] = s;
  __syncthreads();
  const int j = blockIdx.x * 64 + (t & 63);
  const int p = t >> 6;
  float acc = 0.f;
  for (int c = p * 256; c < p * 256 + 256; ++c)
    acc = fmaf(xm[c], W[(size_t)c * C_DIM + j], acc);
  red[p][t & 63] = acc;
  __syncthreads();
  if (t < 64)
    vout[blockIdx.x * 64 + t] = (red[0][t] + red[1][t]) + (red[2][t] + red[3][t]);

  if (do_need && blockIdx.x == 0) {  // fused need-flag computation
    __shared__ int tmor[32], vt[32], am[128], qn[16], kn[16], vn[16], pn[32];
    if (t < 128) am[t] = allmask[t];
    __syncthreads();
    if (t < 32) {
      int o = 0, v = 0;
      for (int qb = 0; qb < T_DIM / 16; ++qb) {
        int tm = tilemask[qb * 32 + t];
        o |= tm;
        v |= ((!am[qb]) && (!tm));
      }
      tmor[t] = o;
      vt[t] = v;
      vtneed[t] = v;
    }
    __syncthreads();
    if (t < 16) {
      int kn_ = tmor[2 * t] | tmor[2 * t + 1];
      kn[t] = kn_;
      kneed[t] = kn_;
      int q = 0;
#pragma unroll
      for (int jj = 0; jj < 8; ++jj) q |= !am[t * 8 + jj];
      qn[t] = q;
      qneed[t] = q;
      int v_ = kn_ | vt[2 * t] | vt[2 * t + 1];
      vn[t] = v_;
      vneed[t] = v_;
    }
    if (t >= 32 && t < 64) {
      int i = t - 32, pp = 0;
#pragma unroll
      for (int jj = 0; jj < 4; ++jj) pp |= !am[i * 4 + jj];
      pn[i] = pp;
      pneed[i] = pp;
    }
    __syncthreads();
    if (t == 0) {
      int a = 0, b = 0, c = 0, d = 0;
      for (int i = 0; i < 16; ++i) { a |= qn[i]; b |= kn[i]; c |= vn[i]; }
      for (int i = 0; i < 32; ++i) d |= pn[i];
      wneed[0] = a; wneed[1] = b; wneed[2] = c; wneed[3] = d;
    }
  }
}

// ---------------- transpose + convert weights (flagged) -------------------------
__global__ __launch_bounds__(256) void transpose_w(const float* __restrict__ W0,
                                                   const float* __restrict__ W1,
                                                   const float* __restrict__ W2,
                                                   const float* __restrict__ W3,
                                                   bf16* __restrict__ O0,
                                                   bf16* __restrict__ O1,
                                                   bf16* __restrict__ O2,
                                                   bf16* __restrict__ O3,
                                                   const int* __restrict__ wneed) {
  if (!wneed[blockIdx.z]) return;
  const float* W = (blockIdx.z == 0) ? W0 : (blockIdx.z == 1) ? W1
                   : (blockIdx.z == 2) ? W2 : W3;
  bf16* O = (blockIdx.z == 0) ? O0 : (blockIdx.z == 1) ? O1
            : (blockIdx.z == 2) ? O2 : O3;
  __shared__ bf16 tile[64][65];
  const int bk = blockIdx.y * 64;
  const int bn = blockIdx.x * 64;
  const int r = threadIdx.x >> 2;
  const int c0 = (threadIdx.x & 3) * 16;
  const float* src = W + (size_t)(bk + r) * C_DIM + bn + c0;
#pragma unroll
  for (int t = 0; t < 16; t += 4) {
    float4 f = *(const float4*)(src + t);
    tile[r][c0 + t + 0] = (bf16)f.x;
    tile[r][c0 + t + 1] = (bf16)f.y;
    tile[r][c0 + t + 2] = (bf16)f.z;
    tile[r][c0 + t + 3] = (bf16)f.w;
  }
  __syncthreads();
  bf16* dst = O + (size_t)(bn + r) * C_DIM + bk + c0;
#pragma unroll
  for (int t = 0; t < 16; ++t) dst[t] = tile[c0 + t][r];
}

// ------- bf16 MFMA GEMM (m97 structure) w/ RoPE+RMS epilogue, vtsum fuse, skip --
// mode=1: QKV (z: q/k/v, flags fq/fk/fv; rope z<2; vtsum z==2); mode=0: proj(fq).
template <int TMt, int MI, int NA>
__global__ __launch_bounds__(256) void gemm_bf16(
    const bf16* __restrict__ A, const bf16* __restrict__ Bt0,
    const bf16* __restrict__ Bt1, const bf16* __restrict__ Bt2, void* C0,
    void* C1, void* C2, int N, int Kd, int bf16_out,
    const float* __restrict__ cosT, const float* __restrict__ sinT,
    const int* __restrict__ fq, const int* __restrict__ fk,
    const int* __restrict__ fv, float* __restrict__ vtsum, int mode) {
  if (mode) {
    const int* f = (blockIdx.z == 0) ? fq : (blockIdx.z == 1) ? fk : fv;
    if (!f[blockIdx.y]) return;
  } else {
    if (!fq[blockIdx.y]) return;
  }
  const bf16* Bt = (blockIdx.z == 0) ? Bt0 : (blockIdx.z == 1) ? Bt1 : Bt2;
  __shared__ __align__(16) bf16 As[TMt * 32];
  __shared__ __align__(16) bf16 Bs[128 * 32];
  const int tid = threadIdx.x;
  const int bm = blockIdx.y * TMt;
  const int bn = blockIdx.x * 128;
  const int wave = tid >> 6, lane = tid & 63;
  const int lr = lane >> 2;
  const int lc = (lane & 3) * 8;
  bf16* gA = (bf16*)(A + (size_t)(bm + wave * 16 * NA + lr) * Kd + lc);
  bf16* gB = (bf16*)(Bt + (size_t)(bn + wave * 32 + lr) * Kd + lc);
  bf16* lA = As + wave * 512 * NA;
  bf16* lB = Bs + wave * 1024;
  const int wr = (wave >> 1) * (MI * 16);
  const int wc = (wave & 1) * 64;
  const int fm = lane & 15;
  const int fk_ = (lane >> 4) * 8;

  f32x4 acc[MI][4] = {};
  for (int k0 = 0; k0 < Kd; k0 += 32) {
    __syncthreads();
#pragma unroll
    for (int u = 0; u < NA; ++u)
      __builtin_amdgcn_global_load_lds(
          (__attribute__((address_space(1))) void*)(gA + (size_t)u * 16 * Kd + k0),
          (__attribute__((address_space(3))) void*)(lA + u * 512), 16, 0, 0);
#pragma unroll
    for (int u = 0; u < 2; ++u)
      __builtin_amdgcn_global_load_lds(
          (__attribute__((address_space(1))) void*)(gB + (size_t)u * 16 * Kd + k0),
          (__attribute__((address_space(3))) void*)(lB + u * 512), 16, 0, 0);
    __syncthreads();
    bf16x8 af[MI], bfr[4];
#pragma unroll
    for (int i = 0; i < MI; ++i)
      af[i] = *(const bf16x8*)(As + (size_t)(wr + i * 16 + fm) * 32 + fk_);
#pragma unroll
    for (int j = 0; j < 4; ++j)
      bfr[j] = *(const bf16x8*)(Bs + (size_t)(wc + j * 16 + fm) * 32 + fk_);
#pragma unroll
    for (int i = 0; i < MI; ++i)
#pragma unroll
      for (int j = 0; j < 4; ++j)
        acc[i][j] = __builtin_amdgcn_mfma_f32_16x16x32_bf16(af[i], bfr[j],
                                                            acc[i][j], 0, 0, 0);
  }
  const int cq = (lane >> 4) * 4;
  if (mode && blockIdx.z < 2) {
    bf16* C = (bf16*)((blockIdx.z == 0) ? C0 : C1);
#pragma unroll
    for (int i = 0; i < MI; ++i)
#pragma unroll
      for (int r = 0; r < 4; ++r) {
        const int t = bm + wr + i * 16 + cq + r;
        float c0 = cosT[(size_t)t * 32 + fm], s0 = sinT[(size_t)t * 32 + fm];
        float c1 = cosT[(size_t)t * 32 + 16 + fm], s1 = sinT[(size_t)t * 32 + 16 + fm];
        float a0 = acc[i][0][r], a1 = acc[i][1][r];
        float a2 = acc[i][2][r], a3 = acc[i][3][r];
        float o0 = a0 * c0 - a2 * s0, o2 = a0 * s0 + a2 * c0;
        float o1 = a1 * c1 - a3 * s1, o3 = a1 * s1 + a3 * c1;
        float ss = o0 * o0 + o1 * o1 + o2 * o2 + o3 * o3;
        ss += __shfl_xor(ss, 1);
        ss += __shfl_xor(ss, 2);
        ss += __shfl_xor(ss, 4);
        ss += __shfl_xor(ss, 8);
        float rn = 1.0f / sqrtf(ss * (1.0f / 64.0f) + 1e-6f);
        size_t base = (size_t)t * N + bn + wc + fm;
        C[base + 0] = (bf16)(o0 * rn);
        C[base + 16] = (bf16)(o1 * rn);
        C[base + 32] = (bf16)(o2 * rn);
        C[base + 48] = (bf16)(o3 * rn);
      }
  } else if (bf16_out) {
    bf16* C = (bf16*)((blockIdx.z == 0) ? C0 : (blockIdx.z == 1) ? C1 : C2);
#pragma unroll
    for (int i = 0; i < MI; ++i)
#pragma unroll
      for (int r = 0; r < 4; ++r) {
        size_t base = (size_t)(bm + wr + i * 16 + cq + r) * N + bn + wc + fm;
#pragma unroll
        for (int j = 0; j < 4; ++j) C[base + j * 16] = (bf16)acc[i][j][r];
      }
    if (mode && blockIdx.z == 2 && MI == 4) {
      // fused vtsum: wave quadrant = one 64-row kt tile x 64 cols (fp32 accs)
      const int kt = (bm + wr) >> 6;
#pragma unroll
      for (int j = 0; j < 4; ++j) {
        float s = 0.f;
#pragma unroll
        for (int i = 0; i < MI; ++i)
#pragma unroll
          for (int r = 0; r < 4; ++r) s += acc[i][j][r];
        s += __shfl_xor(s, 16);
        s += __shfl_xor(s, 32);
        if ((lane >> 4) == 0)
          vtsum[(size_t)kt * C_DIM + bn + wc + j * 16 + fm] = s;
      }
    }
  } else {
    float* C = (float*)((blockIdx.z == 0) ? C0 : (blockIdx.z == 1) ? C1 : C2);
#pragma unroll
    for (int i = 0; i < MI; ++i)
#pragma unroll
      for (int r = 0; r < 4; ++r) {
        size_t base = (size_t)(bm + wr + i * 16 + cq + r) * N + bn + wc + fm;
#pragma unroll
        for (int j = 0; j < 4; ++j) C[base + j * 16] = acc[i][j][r];
      }
  }
}

// ---------------- flash attention w/ tile mask, V sums, all-masked exit ---------
#define QT 16
#define KT 64

__global__ __launch_bounds__(256) void attn2(
    const bf16* __restrict__ q, const bf16* __restrict__ k,
    const bf16* __restrict__ v, const float* __restrict__ qd,
    const float* __restrict__ kd, const float* __restrict__ vtsum,
    const float* __restrict__ vmean, const int* __restrict__ tilemask,
    const int* __restrict__ allmask, const int* __restrict__ pneed,
    bf16* __restrict__ y) {
  const int h = blockIdx.y;
  const int qb = blockIdx.x;
  const int q0 = qb * QT;
  const int tid = threadIdx.x;
  const int q_l = tid >> 4;
  const int sub = tid & 15;

  if (allmask[qb]) {
    // y rows here are only read by proj blocks that actually run
    if (pneed[qb >> 2]) {
      f32x4 vm = *(const f32x4*)(vmean + h * HD_DIM + sub * 4);
      bf16x4 o = {(bf16)vm[0], (bf16)vm[1], (bf16)vm[2], (bf16)vm[3]};
      *(bf16x4*)(y + (size_t)(q0 + q_l) * C_DIM + h * HD_DIM + sub * 4) = o;
    }
    return;
  }

  __shared__ float qs[QT][HD_DIM];
  __shared__ float qds[QT][K_LCP];
  __shared__ float ks[KT][HD_DIM];
  __shared__ float vs[KT][HD_DIM];
  __shared__ float kds[KT][K_LCP];
  __shared__ float sc[QT][KT + 4];

  {
    int r = tid >> 4, c4 = (tid & 15) * 4;
    bf16x4 t4 = *(const bf16x4*)(q + (size_t)(q0 + r) * C_DIM + h * HD_DIM + c4);
    qs[r][c4 + 0] = (float)t4[0] * 0.125f;
    qs[r][c4 + 1] = (float)t4[1] * 0.125f;
    qs[r][c4 + 2] = (float)t4[2] * 0.125f;
    qs[r][c4 + 3] = (float)t4[3] * 0.125f;
    if (tid < QT * K_LCP)
      qds[tid >> 3][tid & 7] = qd[(size_t)(q0 + (tid >> 3)) * K_LCP + (tid & 7)];
  }
  __syncthreads();

  float m = -INFINITY;
  float l = 0.f;
  float acc[4] = {0.f, 0.f, 0.f, 0.f};

  for (int kt = 0; kt < T_DIM / KT; ++kt) {
    if (!tilemask[qb * 32 + kt]) {
      if (m <= NEG_VAL) {
        m = NEG_VAL;
        l += (float)KT;
        f32x4 vt = *(const f32x4*)(vtsum + (size_t)kt * C_DIM + h * HD_DIM + sub * 4);
        acc[0] += vt[0];
        acc[1] += vt[1];
        acc[2] += vt[2];
        acc[3] += vt[3];
      }
      continue;
    }
    const int k0 = kt * KT;
    __syncthreads();
#pragma unroll
    for (int it = 0; it < 4; ++it) {
      int i = tid + it * 256;
      int row = i >> 4, c4 = (i & 15) * 4;
      bf16x4 kv = *(const bf16x4*)(k + (size_t)(k0 + row) * C_DIM + h * HD_DIM + c4);
      bf16x4 vv = *(const bf16x4*)(v + (size_t)(k0 + row) * C_DIM + h * HD_DIM + c4);
      ks[row][c4 + 0] = (float)kv[0];
      ks[row][c4 + 1] = (float)kv[1];
      ks[row][c4 + 2] = (float)kv[2];
      ks[row][c4 + 3] = (float)kv[3];
      vs[row][c4 + 0] = (float)vv[0];
      vs[row][c4 + 1] = (float)vv[1];
      vs[row][c4 + 2] = (float)vv[2];
      vs[row][c4 + 3] = (float)vv[3];
    }
#pragma unroll
    for (int it = 0; it < 2; ++it) {
      int i = tid + it * 256;
      kds[i >> 3][i & 7] = kd[(size_t)(k0 + (i >> 3)) * K_LCP + (i & 7)];
    }
    __syncthreads();

    const int kb = sub * 4;
    bool msk[4];
#pragma unroll
    for (int j = 0; j < 4; ++j) {
      int kg = k0 + kb + j;
      int lcp = 0;
#pragma unroll
      for (int jj = 0; jj < K_LCP; ++jj) {
        if (qds[q_l][jj] == kds[kb + j][jj]) lcp++;
        else break;
      }
      msk[j] = (lcp >= K_LCP - 1) && (kg <= q0 + q_l);
    }
    float s[4] = {0.f, 0.f, 0.f, 0.f};
#pragma unroll
    for (int d4 = 0; d4 < 16; ++d4) {
      float4 q4 = *(const float4*)&qs[q_l][d4 * 4];
#pragma unroll
      for (int j = 0; j < 4; ++j) {
        float4 k4 = *(const float4*)&ks[kb + j][d4 * 4];
        s[j] = fmaf(q4.x, k4.x, s[j]);
        s[j] = fmaf(q4.y, k4.y, s[j]);
        s[j] = fmaf(q4.z, k4.z, s[j]);
        s[j] = fmaf(q4.w, k4.w, s[j]);
      }
    }
    float tmax = NEG_VAL;
#pragma unroll
    for (int j = 0; j < 4; ++j) {
      s[j] = msk[j] ? s[j] : NEG_VAL;
      tmax = fmaxf(tmax, s[j]);
    }
#pragma unroll
    for (int off = 1; off < 16; off <<= 1) tmax = fmaxf(tmax, __shfl_xor(tmax, off));
    float m_new = fmaxf(m, tmax);
    float alpha = expf(m - m_new);
    float lsum = 0.f;
#pragma unroll
    for (int j = 0; j < 4; ++j) {
      float p = expf(s[j] - m_new);
      sc[q_l][kb + j] = p;
      lsum += p;
    }
#pragma unroll
    for (int off = 1; off < 16; off <<= 1) lsum += __shfl_xor(lsum, off);
    l = l * alpha + lsum;
    m = m_new;
    acc[0] *= alpha;
    acc[1] *= alpha;
    acc[2] *= alpha;
    acc[3] *= alpha;
    __syncthreads();
#pragma unroll 8
    for (int kk = 0; kk < KT; ++kk) {
      float w = sc[q_l][kk];
      const float4 v4 = *(const float4*)&vs[kk][sub * 4];
      acc[0] = fmaf(w, v4.x, acc[0]);
      acc[1] = fmaf(w, v4.y, acc[1]);
      acc[2] = fmaf(w, v4.z, acc[2]);
      acc[3] = fmaf(w, v4.w, acc[3]);
    }
  }

  const float inv_l = 1.0f / l;
  bf16x4 o = {(bf16)(acc[0] * inv_l), (bf16)(acc[1] * inv_l),
              (bf16)(acc[2] * inv_l), (bf16)(acc[3] * inv_l)};
  *(bf16x4*)(y + (size_t)(q0 + q_l) * C_DIM + h * HD_DIM + sub * 4) = o;
}

// -------- broadcast rowout into fully-all-masked 64-row out blocks --------------
__global__ __launch_bounds__(256) void bcast_out(const float* __restrict__ rowout,
                                                 const int* __restrict__ pneed,
                                                 float* __restrict__ out) {
  f32x4 v = ((const f32x4*)rowout)[threadIdx.x];
  const int r0 = blockIdx.x * 8;
#pragma unroll
  for (int r = 0; r < 8; ++r) {
    const int row = r0 + r;
    if (pneed[row >> 6]) continue;
    ((f32x4*)(out + (size_t)row * C_DIM))[threadIdx.x] = v;
  }
}

extern "C" void kernel_launch(void* const* d_in, const int* in_sizes, int n_in,
                              void* d_out, int out_size, void* d_ws, size_t ws_size,
                              hipStream_t stream) {
  const float* x = (const float*)d_in[0];
  const float* cosT = (const float*)d_in[1];
  const float* sinT = (const float*)d_in[2];
  const float* Wq = (const float*)d_in[3];
  const float* Wk = (const float*)d_in[4];
  const float* Wv = (const float*)d_in[5];
  const float* Wproj = (const float*)d_in[6];
  const float* Wdq = (const float*)d_in[7];
  const float* Wdk = (const float*)d_in[8];
  float* out = (float*)d_out;

  char* ws = (char*)d_ws;
  const size_t TC2 = (size_t)T_DIM * C_DIM * 2;
  const size_t CC2 = (size_t)C_DIM * C_DIM * 2;
  bf16* xb = (bf16*)(ws + 0);
  bf16* wqt = (bf16*)(ws + TC2);
  bf16* wkt = (bf16*)(ws + TC2 + CC2);
  bf16* wvt = (bf16*)(ws + TC2 + 2 * CC2);
  bf16* wpt = (bf16*)(ws + TC2 + 3 * CC2);
  bf16* qb = (bf16*)(ws + TC2 + 4 * CC2);
  bf16* kb = (bf16*)(ws + 2 * TC2 + 4 * CC2);
  bf16* vb = (bf16*)(ws + 3 * TC2 + 4 * CC2);
  char* p2 = ws + 4 * TC2 + 4 * CC2;
  float* qd = (float*)p2;                      p2 += (size_t)T_DIM * K_LCP * 4;
  float* kd = (float*)p2;                      p2 += (size_t)T_DIM * K_LCP * 4;
  float* vtsum = (float*)p2;                   p2 += 32 * C_DIM * 4;
  float* vmean = (float*)p2;                   p2 += C_DIM * 4;
  float* partial = (float*)p2;                 p2 += 32 * C_DIM * 4;
  float* rowout = (float*)p2;                  p2 += C_DIM * 4;
  int* tilemask = (int*)p2;                    p2 += (T_DIM / 16) * 32 * 4;
  int* allmask = (int*)p2;                     p2 += (T_DIM / 16) * 4;
  int* qneed = (int*)p2;                       p2 += 16 * 4;
  int* kneed = (int*)p2;                       p2 += 16 * 4;
  int* vneed = (int*)p2;                       p2 += 16 * 4;
  int* vtneed = (int*)p2;                      p2 += 32 * 4;
  int* pneed = (int*)p2;                       p2 += 32 * 4;
  int* wneed = (int*)p2;                       p2 += 4 * 4;
  bf16* yb = xb;  // x (bf16) is dead after the QKV GEMM

  convert_qdkd<<<T_DIM / 4, 256, 0, stream>>>(x, Wdq, Wdk, xb, qd, kd);
  tilemask_fused<<<160, 256, 0, stream>>>(qd, kd, x, tilemask, allmask, partial);
  matvec_kernel<<<16, 256, 0, stream>>>(partial, 32, Wv, vmean, 1.0f / 2048.0f,
                                        tilemask, allmask, qneed, kneed, vneed,
                                        vtneed, pneed, wneed, 1);
  matvec_kernel<<<16, 256, 0, stream>>>(vmean, 0, Wproj, rowout, 1.0f, tilemask,
                                        allmask, qneed, kneed, vneed, vtneed,
                                        pneed, wneed, 0);
  transpose_w<<<dim3(16, 16, 4), 256, 0, stream>>>(Wq, Wk, Wv, Wproj, wqt, wkt,
                                                   wvt, wpt, wneed);
  gemm_bf16<128, 4, 2><<<dim3(C_DIM / 128, T_DIM / 128, 3), 256, 0, stream>>>(
      xb, wqt, wkt, wvt, qb, kb, vb, C_DIM, C_DIM, 1, cosT, sinT, qneed, kneed,
      vneed, vtsum, 1);
  attn2<<<dim3(T_DIM / QT, H_NUM), 256, 0, stream>>>(
      qb, kb, vb, qd, kd, vtsum, vmean, tilemask, allmask, pneed, yb);
  gemm_bf16<64, 2, 1><<<dim3(C_DIM / 128, T_DIM / 64, 1), 256, 0, stream>>>(
      yb, wpt, wpt, wpt, out, out, out, C_DIM, C_DIM, 0, cosT, sinT, pneed,
      pneed, pneed, vtsum, 0);
  bcast_out<<<T_DIM / 8, 256, 0, stream>>>(rowout, pneed, out);
}

// Round 7
// 121.576 us; speedup vs baseline: 4.9162x; 1.2160x over previous
//
#include <hip/hip_runtime.h>
#include <math.h>

#define T_DIM 2048
#define C_DIM 1024
#define H_NUM 16
#define HD_DIM 64
#define K_LCP 8
#define NEG_VAL -1.0e9f

typedef __bf16 bf16;
typedef __bf16 bf16x4 __attribute__((ext_vector_type(4)));
typedef __bf16 bf16x8 __attribute__((ext_vector_type(8)));
typedef float f32x4 __attribute__((ext_vector_type(4)));

// ---- shared matvec body: vout[blk*64..] = scale * (reduce(vin) @ W) -----------
__device__ void matvec_body(const float* __restrict__ vin, int npart,
                            const float* __restrict__ W, float* __restrict__ vout,
                            float scale, int blk) {
  __shared__ float xm[C_DIM];
  __shared__ float red[4][64];
  const int t = threadIdx.x;
  f32x4 s = {0.f, 0.f, 0.f, 0.f};
  if (npart) {
    for (int g = 0; g < npart; ++g) s += ((const f32x4*)vin)[g * 256 + t];
  } else {
    s = ((const f32x4*)vin)[t];
  }
  s *= scale;
  *(f32x4*)&xm[t * 4] = s;
  __syncthreads();
  const int j = blk * 64 + (t & 63);
  const int p = t >> 6;
  float acc = 0.f;
  for (int c = p * 256; c < p * 256 + 256; ++c)
    acc = fmaf(xm[c], W[(size_t)c * C_DIM + j], acc);
  red[p][t & 63] = acc;
  __syncthreads();
  if (t < 64)
    vout[blk * 64 + t] = (red[0][t] + red[1][t]) + (red[2][t] + red[3][t]);
}

// ---- A: convert x->bf16 + qd/kd (blocks 0..511), xpartial + flag-zero (512+) --
__global__ __launch_bounds__(256) void fused_a(const float* __restrict__ x,
                                               const float* __restrict__ Wdq,
                                               const float* __restrict__ Wdk,
                                               bf16* __restrict__ xb,
                                               float* __restrict__ qd,
                                               float* __restrict__ kd,
                                               float* __restrict__ partial,
                                               int* __restrict__ flags) {
  const int tid = threadIdx.x;
  if (blockIdx.x >= 512) {  // xpartial arm (+ flag zeroing in block 512)
    const int b = blockIdx.x - 512;
    if (b == 0 && tid < 116) flags[tid] = 0;
    f32x4 s = {0.f, 0.f, 0.f, 0.f};
    for (int r = 0; r < 64; ++r)
      s += ((const f32x4*)(x + (size_t)(b * 64 + r) * C_DIM))[tid];
    ((f32x4*)(partial + (size_t)b * C_DIM))[tid] = s;
    return;
  }
  const int wave = tid >> 6, lane = tid & 63;
  const int t = blockIdx.x * 4 + wave;
  const float* xp = x + (size_t)t * C_DIM;
  bf16* xbp = xb + (size_t)t * C_DIM;
  float aq[8] = {}, ak[8] = {};
#pragma unroll
  for (int i = 0; i < 16; ++i) {
    const int c = i * 64 + lane;
    float xv = xp[c];
    xbp[c] = (bf16)xv;
    float4 wq0 = *(const float4*)(Wdq + (size_t)c * K_LCP);
    float4 wq1 = *(const float4*)(Wdq + (size_t)c * K_LCP + 4);
    float4 wk0 = *(const float4*)(Wdk + (size_t)c * K_LCP);
    float4 wk1 = *(const float4*)(Wdk + (size_t)c * K_LCP + 4);
    aq[0] = fmaf(xv, wq0.x, aq[0]); aq[1] = fmaf(xv, wq0.y, aq[1]);
    aq[2] = fmaf(xv, wq0.z, aq[2]); aq[3] = fmaf(xv, wq0.w, aq[3]);
    aq[4] = fmaf(xv, wq1.x, aq[4]); aq[5] = fmaf(xv, wq1.y, aq[5]);
    aq[6] = fmaf(xv, wq1.z, aq[6]); aq[7] = fmaf(xv, wq1.w, aq[7]);
    ak[0] = fmaf(xv, wk0.x, ak[0]); ak[1] = fmaf(xv, wk0.y, ak[1]);
    ak[2] = fmaf(xv, wk0.z, ak[2]); ak[3] = fmaf(xv, wk0.w, ak[3]);
    ak[4] = fmaf(xv, wk1.x, ak[4]); ak[5] = fmaf(xv, wk1.y, ak[5]);
    ak[6] = fmaf(xv, wk1.z, ak[6]); ak[7] = fmaf(xv, wk1.w, ak[7]);
  }
#pragma unroll
  for (int j = 0; j < 8; ++j) {
#pragma unroll
    for (int off = 32; off >= 1; off >>= 1) {
      aq[j] += __shfl_xor(aq[j], off);
      ak[j] += __shfl_xor(ak[j], off);
    }
  }
  if (lane == 0) {
    *(float4*)(qd + (size_t)t * K_LCP) = make_float4(aq[0], aq[1], aq[2], aq[3]);
    *(float4*)(qd + (size_t)t * K_LCP + 4) = make_float4(aq[4], aq[5], aq[6], aq[7]);
    *(float4*)(kd + (size_t)t * K_LCP) = make_float4(ak[0], ak[1], ak[2], ak[3]);
    *(float4*)(kd + (size_t)t * K_LCP + 4) = make_float4(ak[4], ak[5], ak[6], ak[7]);
  }
}

// ---- B: tilemask + atomic need flags (blocks 0..127), matvec1 arm (128..143) --
__global__ __launch_bounds__(256) void fused_b(
    const float* __restrict__ qd, const float* __restrict__ kd,
    const float* __restrict__ partial, const float* __restrict__ Wv,
    int* __restrict__ tilemask, int* __restrict__ allmask,
    float* __restrict__ vmean, int* __restrict__ qneed, int* __restrict__ kneed,
    int* __restrict__ vneed, int* __restrict__ vtneed, int* __restrict__ pneed,
    int* __restrict__ wneed) {
  const int tid = threadIdx.x;
  if (blockIdx.x >= 128) {  // matvec1 arm: vmean = (colmean x) @ Wv
    matvec_body(partial, 32, Wv, vmean, 1.0f / 2048.0f, blockIdx.x - 128);
    return;
  }
  const int qb = blockIdx.x;
  __shared__ float qds[16][K_LCP];
  __shared__ int tm[32];
  if (tid < 32) tm[tid] = 0;
  if (tid < 16 * K_LCP)
    qds[tid >> 3][tid & 7] = qd[(size_t)(qb * 16 + (tid >> 3)) * K_LCP + (tid & 7)];
  __syncthreads();
  for (int key = tid; key < T_DIM; key += 256) {
    float kv[K_LCP];
    *(float4*)&kv[0] = *(const float4*)(kd + (size_t)key * K_LCP);
    *(float4*)&kv[4] = *(const float4*)(kd + (size_t)key * K_LCP + 4);
    int any = 0;
#pragma unroll
    for (int ql = 0; ql < 16; ++ql) {
      int qg = qb * 16 + ql;
      if (key > qg) continue;
      int lcp = 0;
#pragma unroll
      for (int jj = 0; jj < K_LCP; ++jj) {
        if (qds[ql][jj] == kv[jj]) lcp++;
        else break;
      }
      if (lcp >= K_LCP - 1) any = 1;
    }
    if (any) tm[key >> 6] = 1;  // benign race: same value
  }
  __syncthreads();
  int anytm = 0;
#pragma unroll
  for (int i = 0; i < 32; ++i) anytm |= tm[i];
  if (tid < 32) tilemask[qb * 32 + tid] = tm[tid];
  if (tid == 0) allmask[qb] = !anytm;
  if (anytm) {  // device-scope atomics; flags pre-zeroed by launch A
    if (tid < 32) {
      if (tm[tid]) {
        atomicOr(&kneed[tid >> 1], 1);
        atomicOr(&vneed[tid >> 1], 1);
      } else {
        atomicOr(&vtneed[tid], 1);
        atomicOr(&vneed[tid >> 1], 1);
      }
    }
    if (tid == 0) {
      atomicOr(&qneed[qb >> 3], 1);
      atomicOr(&pneed[qb >> 2], 1);
      atomicOr(&wneed[0], 1);
      atomicOr(&wneed[1], 1);
      atomicOr(&wneed[2], 1);
      atomicOr(&wneed[3], 1);
    }
  }
}

// ---- E: matvec2 arm (blocks 0..15) + flagged weight transpose (16..1039) -------
__global__ __launch_bounds__(256) void fused_e(
    const float* __restrict__ vmean, const float* __restrict__ WprojF,
    float* __restrict__ rowout, const float* __restrict__ W0,
    const float* __restrict__ W1, const float* __restrict__ W2,
    const float* __restrict__ W3, bf16* __restrict__ O0, bf16* __restrict__ O1,
    bf16* __restrict__ O2, bf16* __restrict__ O3, const int* __restrict__ wneed) {
  if (blockIdx.x < 16) {  // rowout = vmean @ Wproj
    matvec_body(vmean, 0, WprojF, rowout, 1.0f, blockIdx.x);
    return;
  }
  const int idx = blockIdx.x - 16;  // 0..1023
  const int z = idx >> 8;
  if (!wneed[z]) return;
  const float* W = (z == 0) ? W0 : (z == 1) ? W1 : (z == 2) ? W2 : W3;
  bf16* O = (z == 0) ? O0 : (z == 1) ? O1 : (z == 2) ? O2 : O3;
  __shared__ bf16 tile[64][65];
  const int rem = idx & 255;
  const int bk = (rem >> 4) * 64;
  const int bn = (rem & 15) * 64;
  const int r = threadIdx.x >> 2;
  const int c0 = (threadIdx.x & 3) * 16;
  const float* src = W + (size_t)(bk + r) * C_DIM + bn + c0;
#pragma unroll
  for (int t = 0; t < 16; t += 4) {
    float4 f = *(const float4*)(src + t);
    tile[r][c0 + t + 0] = (bf16)f.x;
    tile[r][c0 + t + 1] = (bf16)f.y;
    tile[r][c0 + t + 2] = (bf16)f.z;
    tile[r][c0 + t + 3] = (bf16)f.w;
  }
  __syncthreads();
  bf16* dst = O + (size_t)(bn + r) * C_DIM + bk + c0;
#pragma unroll
  for (int t = 0; t < 16; ++t) dst[t] = tile[c0 + t][r];
}

// ------- bf16 MFMA GEMM w/ RoPE+RMS epilogue, vtsum fuse, skip, bcast arm -------
// mode=1: QKV (z: q/k/v, flags fq/fk/fv; rope z<2; vtsum z==2).
// mode=0: proj (flag fq=pneed; z==1 is the bcast arm writing !pneed out rows).
template <int TMt, int MI, int NA>
__global__ __launch_bounds__(256) void gemm_bf16(
    const bf16* __restrict__ A, const bf16* __restrict__ Bt0,
    const bf16* __restrict__ Bt1, const bf16* __restrict__ Bt2, void* C0,
    void* C1, void* C2, int N, int Kd, int bf16_out,
    const float* __restrict__ cosT, const float* __restrict__ sinT,
    const int* __restrict__ fq, const int* __restrict__ fk,
    const int* __restrict__ fv, float* __restrict__ vtsum,
    const float* __restrict__ rowout, int mode) {
  if (!mode && blockIdx.z == 1) {  // bcast arm
    const int b = blockIdx.y * 8 + blockIdx.x;  // 0..255
    f32x4 v = ((const f32x4*)rowout)[threadIdx.x];
#pragma unroll
    for (int r = 0; r < 8; ++r) {
      const int row = b * 8 + r;
      if (fq[row >> 6]) continue;
      ((f32x4*)((float*)C0 + (size_t)row * C_DIM))[threadIdx.x] = v;
    }
    return;
  }
  if (mode) {
    const int* f = (blockIdx.z == 0) ? fq : (blockIdx.z == 1) ? fk : fv;
    if (!f[blockIdx.y]) return;
  } else {
    if (!fq[blockIdx.y]) return;
  }
  const bf16* Bt = (blockIdx.z == 0) ? Bt0 : (blockIdx.z == 1) ? Bt1 : Bt2;
  __shared__ __align__(16) bf16 As[TMt * 32];
  __shared__ __align__(16) bf16 Bs[128 * 32];
  const int tid = threadIdx.x;
  const int bm = blockIdx.y * TMt;
  const int bn = blockIdx.x * 128;
  const int wave = tid >> 6, lane = tid & 63;
  const int lr = lane >> 2;
  const int lc = (lane & 3) * 8;
  bf16* gA = (bf16*)(A + (size_t)(bm + wave * 16 * NA + lr) * Kd + lc);
  bf16* gB = (bf16*)(Bt + (size_t)(bn + wave * 32 + lr) * Kd + lc);
  bf16* lA = As + wave * 512 * NA;
  bf16* lB = Bs + wave * 1024;
  const int wr = (wave >> 1) * (MI * 16);
  const int wc = (wave & 1) * 64;
  const int fm = lane & 15;
  const int fk_ = (lane >> 4) * 8;

  f32x4 acc[MI][4] = {};
  for (int k0 = 0; k0 < Kd; k0 += 32) {
    __syncthreads();
#pragma unroll
    for (int u = 0; u < NA; ++u)
      __builtin_amdgcn_global_load_lds(
          (__attribute__((address_space(1))) void*)(gA + (size_t)u * 16 * Kd + k0),
          (__attribute__((address_space(3))) void*)(lA + u * 512), 16, 0, 0);
#pragma unroll
    for (int u = 0; u < 2; ++u)
      __builtin_amdgcn_global_load_lds(
          (__attribute__((address_space(1))) void*)(gB + (size_t)u * 16 * Kd + k0),
          (__attribute__((address_space(3))) void*)(lB + u * 512), 16, 0, 0);
    __syncthreads();
    bf16x8 af[MI], bfr[4];
#pragma unroll
    for (int i = 0; i < MI; ++i)
      af[i] = *(const bf16x8*)(As + (size_t)(wr + i * 16 + fm) * 32 + fk_);
#pragma unroll
    for (int j = 0; j < 4; ++j)
      bfr[j] = *(const bf16x8*)(Bs + (size_t)(wc + j * 16 + fm) * 32 + fk_);
#pragma unroll
    for (int i = 0; i < MI; ++i)
#pragma unroll
      for (int j = 0; j < 4; ++j)
        acc[i][j] = __builtin_amdgcn_mfma_f32_16x16x32_bf16(af[i], bfr[j],
                                                            acc[i][j], 0, 0, 0);
  }
  const int cq = (lane >> 4) * 4;
  if (mode && blockIdx.z < 2) {
    bf16* C = (bf16*)((blockIdx.z == 0) ? C0 : C1);
#pragma unroll
    for (int i = 0; i < MI; ++i)
#pragma unroll
      for (int r = 0; r < 4; ++r) {
        const int t = bm + wr + i * 16 + cq + r;
        float c0 = cosT[(size_t)t * 32 + fm], s0 = sinT[(size_t)t * 32 + fm];
        float c1 = cosT[(size_t)t * 32 + 16 + fm], s1 = sinT[(size_t)t * 32 + 16 + fm];
        float a0 = acc[i][0][r], a1 = acc[i][1][r];
        float a2 = acc[i][2][r], a3 = acc[i][3][r];
        float o0 = a0 * c0 - a2 * s0, o2 = a0 * s0 + a2 * c0;
        float o1 = a1 * c1 - a3 * s1, o3 = a1 * s1 + a3 * c1;
        float ss = o0 * o0 + o1 * o1 + o2 * o2 + o3 * o3;
        ss += __shfl_xor(ss, 1);
        ss += __shfl_xor(ss, 2);
        ss += __shfl_xor(ss, 4);
        ss += __shfl_xor(ss, 8);
        float rn = 1.0f / sqrtf(ss * (1.0f / 64.0f) + 1e-6f);
        size_t base = (size_t)t * N + bn + wc + fm;
        C[base + 0] = (bf16)(o0 * rn);
        C[base + 16] = (bf16)(o1 * rn);
        C[base + 32] = (bf16)(o2 * rn);
        C[base + 48] = (bf16)(o3 * rn);
      }
  } else if (bf16_out) {
    bf16* C = (bf16*)((blockIdx.z == 0) ? C0 : (blockIdx.z == 1) ? C1 : C2);
#pragma unroll
    for (int i = 0; i < MI; ++i)
#pragma unroll
      for (int r = 0; r < 4; ++r) {
        size_t base = (size_t)(bm + wr + i * 16 + cq + r) * N + bn + wc + fm;
#pragma unroll
        for (int j = 0; j < 4; ++j) C[base + j * 16] = (bf16)acc[i][j][r];
      }
    if (mode && blockIdx.z == 2 && MI == 4) {
      // fused vtsum: wave quadrant = one 64-row kt tile x 64 cols (fp32 accs)
      const int kt = (bm + wr) >> 6;
#pragma unroll
      for (int j = 0; j < 4; ++j) {
        float s = 0.f;
#pragma unroll
        for (int i = 0; i < MI; ++i)
#pragma unroll
          for (int r = 0; r < 4; ++r) s += acc[i][j][r];
        s += __shfl_xor(s, 16);
        s += __shfl_xor(s, 32);
        if ((lane >> 4) == 0)
          vtsum[(size_t)kt * C_DIM + bn + wc + j * 16 + fm] = s;
      }
    }
  } else {
    float* C = (float*)((blockIdx.z == 0) ? C0 : (blockIdx.z == 1) ? C1 : C2);
#pragma unroll
    for (int i = 0; i < MI; ++i)
#pragma unroll
      for (int r = 0; r < 4; ++r) {
        size_t base = (size_t)(bm + wr + i * 16 + cq + r) * N + bn + wc + fm;
#pragma unroll
        for (int j = 0; j < 4; ++j) C[base + j * 16] = acc[i][j][r];
      }
  }
}

// ---------------- flash attention w/ tile mask, V sums, all-masked exit ---------
#define QT 16
#define KT 64

__global__ __launch_bounds__(256) void attn2(
    const bf16* __restrict__ q, const bf16* __restrict__ k,
    const bf16* __restrict__ v, const float* __restrict__ qd,
    const float* __restrict__ kd, const float* __restrict__ vtsum,
    const float* __restrict__ vmean, const int* __restrict__ tilemask,
    const int* __restrict__ allmask, const int* __restrict__ pneed,
    bf16* __restrict__ y) {
  const int h = blockIdx.y;
  const int qb = blockIdx.x;
  const int q0 = qb * QT;
  const int tid = threadIdx.x;
  const int q_l = tid >> 4;
  const int sub = tid & 15;

  if (allmask[qb]) {
    if (pneed[qb >> 2]) {
      f32x4 vm = *(const f32x4*)(vmean + h * HD_DIM + sub * 4);
      bf16x4 o = {(bf16)vm[0], (bf16)vm[1], (bf16)vm[2], (bf16)vm[3]};
      *(bf16x4*)(y + (size_t)(q0 + q_l) * C_DIM + h * HD_DIM + sub * 4) = o;
    }
    return;
  }

  __shared__ float qs[QT][HD_DIM];
  __shared__ float qds[QT][K_LCP];
  __shared__ float ks[KT][HD_DIM];
  __shared__ float vs[KT][HD_DIM];
  __shared__ float kds[KT][K_LCP];
  __shared__ float sc[QT][KT + 4];

  {
    int r = tid >> 4, c4 = (tid & 15) * 4;
    bf16x4 t4 = *(const bf16x4*)(q + (size_t)(q0 + r) * C_DIM + h * HD_DIM + c4);
    qs[r][c4 + 0] = (float)t4[0] * 0.125f;
    qs[r][c4 + 1] = (float)t4[1] * 0.125f;
    qs[r][c4 + 2] = (float)t4[2] * 0.125f;
    qs[r][c4 + 3] = (float)t4[3] * 0.125f;
    if (tid < QT * K_LCP)
      qds[tid >> 3][tid & 7] = qd[(size_t)(q0 + (tid >> 3)) * K_LCP + (tid & 7)];
  }
  __syncthreads();

  float m = -INFINITY;
  float l = 0.f;
  float acc[4] = {0.f, 0.f, 0.f, 0.f};

  for (int kt = 0; kt < T_DIM / KT; ++kt) {
    if (!tilemask[qb * 32 + kt]) {
      if (m <= NEG_VAL) {
        m = NEG_VAL;
        l += (float)KT;
        f32x4 vt = *(const f32x4*)(vtsum + (size_t)kt * C_DIM + h * HD_DIM + sub * 4);
        acc[0] += vt[0];
        acc[1] += vt[1];
        acc[2] += vt[2];
        acc[3] += vt[3];
      }
      continue;
    }
    const int k0 = kt * KT;
    __syncthreads();
#pragma unroll
    for (int it = 0; it < 4; ++it) {
      int i = tid + it * 256;
      int row = i >> 4, c4 = (i & 15) * 4;
      bf16x4 kv = *(const bf16x4*)(k + (size_t)(k0 + row) * C_DIM + h * HD_DIM + c4);
      bf16x4 vv = *(const bf16x4*)(v + (size_t)(k0 + row) * C_DIM + h * HD_DIM + c4);
      ks[row][c4 + 0] = (float)kv[0];
      ks[row][c4 + 1] = (float)kv[1];
      ks[row][c4 + 2] = (float)kv[2];
      ks[row][c4 + 3] = (float)kv[3];
      vs[row][c4 + 0] = (float)vv[0];
      vs[row][c4 + 1] = (float)vv[1];
      vs[row][c4 + 2] = (float)vv[2];
      vs[row][c4 + 3] = (float)vv[3];
    }
#pragma unroll
    for (int it = 0; it < 2; ++it) {
      int i = tid + it * 256;
      kds[i >> 3][i & 7] = kd[(size_t)(k0 + (i >> 3)) * K_LCP + (i & 7)];
    }
    __syncthreads();

    const int kb = sub * 4;
    bool msk[4];
#pragma unroll
    for (int j = 0; j < 4; ++j) {
      int kg = k0 + kb + j;
      int lcp = 0;
#pragma unroll
      for (int jj = 0; jj < K_LCP; ++jj) {
        if (qds[q_l][jj] == kds[kb + j][jj]) lcp++;
        else break;
      }
      msk[j] = (lcp >= K_LCP - 1) && (kg <= q0 + q_l);
    }
    float s[4] = {0.f, 0.f, 0.f, 0.f};
#pragma unroll
    for (int d4 = 0; d4 < 16; ++d4) {
      float4 q4 = *(const float4*)&qs[q_l][d4 * 4];
#pragma unroll
      for (int j = 0; j < 4; ++j) {
        float4 k4 = *(const float4*)&ks[kb + j][d4 * 4];
        s[j] = fmaf(q4.x, k4.x, s[j]);
        s[j] = fmaf(q4.y, k4.y, s[j]);
        s[j] = fmaf(q4.z, k4.z, s[j]);
        s[j] = fmaf(q4.w, k4.w, s[j]);
      }
    }
    float tmax = NEG_VAL;
#pragma unroll
    for (int j = 0; j < 4; ++j) {
      s[j] = msk[j] ? s[j] : NEG_VAL;
      tmax = fmaxf(tmax, s[j]);
    }
#pragma unroll
    for (int off = 1; off < 16; off <<= 1) tmax = fmaxf(tmax, __shfl_xor(tmax, off));
    float m_new = fmaxf(m, tmax);
    float alpha = expf(m - m_new);
    float lsum = 0.f;
#pragma unroll
    for (int j = 0; j < 4; ++j) {
      float p = expf(s[j] - m_new);
      sc[q_l][kb + j] = p;
      lsum += p;
    }
#pragma unroll
    for (int off = 1; off < 16; off <<= 1) lsum += __shfl_xor(lsum, off);
    l = l * alpha + lsum;
    m = m_new;
    acc[0] *= alpha;
    acc[1] *= alpha;
    acc[2] *= alpha;
    acc[3] *= alpha;
    __syncthreads();
#pragma unroll 8
    for (int kk = 0; kk < KT; ++kk) {
      float w = sc[q_l][kk];
      const float4 v4 = *(const float4*)&vs[kk][sub * 4];
      acc[0] = fmaf(w, v4.x, acc[0]);
      acc[1] = fmaf(w, v4.y, acc[1]);
      acc[2] = fmaf(w, v4.z, acc[2]);
      acc[3] = fmaf(w, v4.w, acc[3]);
    }
  }

  const float inv_l = 1.0f / l;
  bf16x4 o = {(bf16)(acc[0] * inv_l), (bf16)(acc[1] * inv_l),
              (bf16)(acc[2] * inv_l), (bf16)(acc[3] * inv_l)};
  *(bf16x4*)(y + (size_t)(q0 + q_l) * C_DIM + h * HD_DIM + sub * 4) = o;
}

extern "C" void kernel_launch(void* const* d_in, const int* in_sizes, int n_in,
                              void* d_out, int out_size, void* d_ws, size_t ws_size,
                              hipStream_t stream) {
  const float* x = (const float*)d_in[0];
  const float* cosT = (const float*)d_in[1];
  const float* sinT = (const float*)d_in[2];
  const float* Wq = (const float*)d_in[3];
  const float* Wk = (const float*)d_in[4];
  const float* Wv = (const float*)d_in[5];
  const float* Wproj = (const float*)d_in[6];
  const float* Wdq = (const float*)d_in[7];
  const float* Wdk = (const float*)d_in[8];
  float* out = (float*)d_out;

  char* ws = (char*)d_ws;
  const size_t TC2 = (size_t)T_DIM * C_DIM * 2;
  const size_t CC2 = (size_t)C_DIM * C_DIM * 2;
  bf16* xb = (bf16*)(ws + 0);
  bf16* wqt = (bf16*)(ws + TC2);
  bf16* wkt = (bf16*)(ws + TC2 + CC2);
  bf16* wvt = (bf16*)(ws + TC2 + 2 * CC2);
  bf16* wpt = (bf16*)(ws + TC2 + 3 * CC2);
  bf16* qb = (bf16*)(ws + TC2 + 4 * CC2);
  bf16* kb = (bf16*)(ws + 2 * TC2 + 4 * CC2);
  bf16* vb = (bf16*)(ws + 3 * TC2 + 4 * CC2);
  char* p2 = ws + 4 * TC2 + 4 * CC2;
  float* qd = (float*)p2;                      p2 += (size_t)T_DIM * K_LCP * 4;
  float* kd = (float*)p2;                      p2 += (size_t)T_DIM * K_LCP * 4;
  float* vtsum = (float*)p2;                   p2 += 32 * C_DIM * 4;
  float* vmean = (float*)p2;                   p2 += C_DIM * 4;
  float* partial = (float*)p2;                 p2 += 32 * C_DIM * 4;
  float* rowout = (float*)p2;                  p2 += C_DIM * 4;
  int* tilemask = (int*)p2;                    p2 += (T_DIM / 16) * 32 * 4;
  int* allmask = (int*)p2;                     p2 += (T_DIM / 16) * 4;
  // flags contiguous (zeroed as one 116-int array by fused_a)
  int* qneed = (int*)p2;                       p2 += 16 * 4;
  int* kneed = (int*)p2;                       p2 += 16 * 4;
  int* vneed = (int*)p2;                       p2 += 16 * 4;
  int* vtneed = (int*)p2;                      p2 += 32 * 4;
  int* pneed = (int*)p2;                       p2 += 32 * 4;
  int* wneed = (int*)p2;                       p2 += 4 * 4;
  bf16* yb = xb;  // x (bf16) is dead after the QKV GEMM

  fused_a<<<544, 256, 0, stream>>>(x, Wdq, Wdk, xb, qd, kd, partial, qneed);
  fused_b<<<144, 256, 0, stream>>>(qd, kd, partial, Wv, tilemask, allmask,
                                   vmean, qneed, kneed, vneed, vtneed, pneed,
                                   wneed);
  fused_e<<<16 + 1024, 256, 0, stream>>>(vmean, Wproj, rowout, Wq, Wk, Wv,
                                         Wproj, wqt, wkt, wvt, wpt, wneed);
  gemm_bf16<128, 4, 2><<<dim3(C_DIM / 128, T_DIM / 128, 3), 256, 0, stream>>>(
      xb, wqt, wkt, wvt, qb, kb, vb, C_DIM, C_DIM, 1, cosT, sinT, qneed, kneed,
      vneed, vtsum, rowout, 1);
  attn2<<<dim3(T_DIM / QT, H_NUM), 256, 0, stream>>>(
      qb, kb, vb, qd, kd, vtsum, vmean, tilemask, allmask, pneed, yb);
  gemm_bf16<64, 2, 1><<<dim3(C_DIM / 128, T_DIM / 64, 2), 256, 0, stream>>>(
      yb, wpt, wpt, wpt, out, out, out, C_DIM, C_DIM, 0, cosT, sinT, pneed,
      pneed, pneed, vtsum, rowout, 0);
}